// Round 1
// baseline (501.605 us; speedup 1.0000x reference)
//
#include <hip/hip_runtime.h>

// Decoder block: B=2 T=2048 D=1024 H=16 hd=64 HIDDEN=4096. All f32 in/out,
// bf16 MFMA internally (threshold is bf16-floor).
//
// Pipeline (all on `stream`):
//  1. transpose+cvt weights f32(K,N) -> bf16(N,K)      (4 launches)
//  2. rope cos/sin table (T x 32 f32x2)
//  3. LN1: x -> h1 bf16
//  4. GEMM qkv = h1 @ Wqkv             (EPI 0: plain bf16 out)
//  5. rope_apply: qkv -> Q,K (B,H,T,hd) and V^T (B,H,hd,T) bf16
//  6. attention (flash, causal) -> attn bf16 (M,D)
//  7. GEMM x2 = attn @ Wo + x          (EPI 1: +resid, f32 out)
//  8. LN2: x2 -> h2 bf16
//  9. GEMM mid = gelu(h2 @ W1 + b1)    (EPI 2: +bias,gelu, bf16 out)
// 10. GEMM out = mid @ W2 + b2 + x2    (EPI 3: +bias+resid, f32 out)

typedef __bf16 bf16_t;
typedef bf16_t bf16x8 __attribute__((ext_vector_type(8)));
typedef float f32x4 __attribute__((ext_vector_type(4)));

#define M_ROWS 4096   // B*T
#define DMODEL 1024
#define TSEQ   2048
#define NHEAD  16
#define HDIM   64

__device__ __forceinline__ ushort f2bf(float f) {
  union { float f; unsigned u; } v; v.f = f;
  unsigned r = (v.u + 0x7fffu + ((v.u >> 16) & 1u)) >> 16;
  return (ushort)r;
}
__device__ __forceinline__ float bf2f(ushort u) {
  union { unsigned u; float f; } v; v.u = ((unsigned)u) << 16;
  return v.f;
}
__device__ __forceinline__ void gload_lds16(const void* g, void* l) {
  __builtin_amdgcn_global_load_lds(
      (const __attribute__((address_space(1))) unsigned*)g,
      (__attribute__((address_space(3))) unsigned*)l, 16, 0, 0);
}
__device__ __forceinline__ f32x4 mfma16(bf16x8 a, bf16x8 b, f32x4 c) {
  return __builtin_amdgcn_mfma_f32_16x16x32_bf16(a, b, c, 0, 0, 0);
}
__device__ __forceinline__ float gelu_f(float x) {
  float y = 0.7978845608028654f * (x + 0.044715f * x * x * x);
  float e = __expf(2.0f * y);
  float t = 1.0f - 2.0f / (e + 1.0f);   // tanh(y), overflow-safe
  return 0.5f * x * (1.0f + t);
}

// ---------------- weight transpose + f32->bf16 -----------------------------
// src: (K,N) f32 row-major. dst: (N,K) bf16 row-major. grid (N/32, K/32).
__global__ __launch_bounds__(256)
void transpose_bf16(const float* __restrict__ src, ushort* __restrict__ dst,
                    int K, int N) {
  __shared__ float t[32][33];
  int n0 = blockIdx.x * 32, k0 = blockIdx.y * 32;
  int tx = threadIdx.x & 31, ty = threadIdx.x >> 5;  // ty in [0,8)
#pragma unroll
  for (int i = 0; i < 4; i++) {
    int k = ty + i * 8;
    t[k][tx] = src[(size_t)(k0 + k) * N + n0 + tx];
  }
  __syncthreads();
#pragma unroll
  for (int i = 0; i < 4; i++) {
    int nn = ty + i * 8;
    dst[(size_t)(n0 + nn) * K + k0 + tx] = f2bf(t[tx][nn]);
  }
}

// ---------------- layernorm (f32 in, bf16 out) -----------------------------
__global__ __launch_bounds__(256)
void ln_kernel(const float* __restrict__ x, const float* __restrict__ sc,
               const float* __restrict__ bi, ushort* __restrict__ out) {
  int row = blockIdx.x;
  int tid = threadIdx.x;
  const float4 v = *(const float4*)&x[(size_t)row * DMODEL + tid * 4];
  float s = v.x + v.y + v.z + v.w;
  float s2 = v.x * v.x + v.y * v.y + v.z * v.z + v.w * v.w;
#pragma unroll
  for (int off = 32; off > 0; off >>= 1) {
    s += __shfl_down(s, off);
    s2 += __shfl_down(s2, off);
  }
  __shared__ float red[8];
  int lane = tid & 63, w = tid >> 6;
  if (lane == 0) { red[w * 2] = s; red[w * 2 + 1] = s2; }
  __syncthreads();
  float S = red[0] + red[2] + red[4] + red[6];
  float S2 = red[1] + red[3] + red[5] + red[7];
  float mu = S * (1.0f / DMODEL);
  float var = S2 * (1.0f / DMODEL) - mu * mu;
  float rs = rsqrtf(var + 1e-6f);
  float4 scv = *(const float4*)&sc[tid * 4];
  float4 biv = *(const float4*)&bi[tid * 4];
  ushort4 o;
  o.x = f2bf((v.x - mu) * rs * scv.x + biv.x);
  o.y = f2bf((v.y - mu) * rs * scv.y + biv.y);
  o.z = f2bf((v.z - mu) * rs * scv.z + biv.z);
  o.w = f2bf((v.w - mu) * rs * scv.w + biv.w);
  *(ushort4*)&out[(size_t)row * DMODEL + tid * 4] = o;
}

// ---------------- rope table -----------------------------------------------
__global__ __launch_bounds__(256)
void rope_table(const int* __restrict__ positions, float2* __restrict__ tab) {
  int i = blockIdx.x * 256 + threadIdx.x;  // T*32
  int t = i >> 5, f = i & 31;
  float inv = __expf(-(float)f * (1.0f / 32.0f) * 9.210340371976184f);  // ln(10000)
  float a = (float)positions[t] * inv;
  tab[i] = make_float2(cosf(a), sinf(a));
}

// ---------------- rope apply + QKV reshape ---------------------------------
// qkv: (B*T, 3*D) bf16. Q,K: (B,H,T,hd). VT: (B,H,hd,T).
__global__ __launch_bounds__(256)
void rope_apply(const ushort* __restrict__ qkv, const float2* __restrict__ tab,
                ushort* __restrict__ Q, ushort* __restrict__ Kd,
                ushort* __restrict__ VT) {
  int i = blockIdx.x * 256 + threadIdx.x;  // B*T*H*32
  int f = i & 31;
  int h = (i >> 5) & 15;
  int t = (i >> 9) & 2047;
  int b = i >> 20;
  int row = b * TSEQ + t;
  const ushort* qr = qkv + (size_t)row * 3072;
  float2 cs = tab[t * 32 + f];
  float c = cs.x, s = cs.y;
  float q1 = bf2f(qr[h * 64 + f]),        q2 = bf2f(qr[h * 64 + 32 + f]);
  float k1 = bf2f(qr[1024 + h * 64 + f]), k2 = bf2f(qr[1024 + h * 64 + 32 + f]);
  float v1 = bf2f(qr[2048 + h * 64 + f]), v2 = bf2f(qr[2048 + h * 64 + 32 + f]);
  size_t bh = (size_t)(b * NHEAD + h);
  ushort* Qp = Q + bh * TSEQ * HDIM + (size_t)t * HDIM;
  ushort* Kp = Kd + bh * TSEQ * HDIM + (size_t)t * HDIM;
  Qp[f]      = f2bf(q1 * c - q2 * s);
  Qp[f + 32] = f2bf(q1 * s + q2 * c);
  Kp[f]      = f2bf(k1 * c - k2 * s);
  Kp[f + 32] = f2bf(k1 * s + k2 * c);
  ushort* Vp = VT + bh * HDIM * TSEQ;
  Vp[(size_t)f * TSEQ + t] = f2bf(v1);
  Vp[(size_t)(f + 32) * TSEQ + t] = f2bf(v2);
}

// ---------------- attention (flash, causal) --------------------------------
// grid (T/64, B*H), 256 thr = 4 waves, wave w owns q-rows qb*64+w*16..+16.
__global__ __launch_bounds__(256)
void attn_kernel(const ushort* __restrict__ Q, const ushort* __restrict__ Kd,
                 const ushort* __restrict__ VT, ushort* __restrict__ O) {
  int qb = blockIdx.x;
  int bh = blockIdx.y;
  int tid = threadIdx.x, lane = tid & 63, w = tid >> 6;
  int qw = qb * 64 + w * 16;
  const ushort* Qb = Q + (size_t)bh * TSEQ * HDIM;
  const ushort* Kb = Kd + (size_t)bh * TSEQ * HDIM;
  const ushort* Vb = VT + (size_t)bh * HDIM * TSEQ;

  __shared__ ushort lp[4][16 * 32];
  ushort* myp = lp[w];

  int lr = lane & 15, lg = lane >> 4;
  bf16x8 aq0 = *(const bf16x8*)&Qb[(size_t)(qw + lr) * HDIM + lg * 8];
  bf16x8 aq1 = *(const bf16x8*)&Qb[(size_t)(qw + lr) * HDIM + 32 + lg * 8];

  float m_run[4], l_run[4];
  f32x4 o[4] = {};
#pragma unroll
  for (int r = 0; r < 4; r++) { m_run[r] = -1e30f; l_run[r] = 0.0f; }

  int nt = 2 * qb + 2;  // uniform over block: covers rows up to qb*64+63
  for (int it = 0; it < nt; ++it) {
    int kt = it * 32;
    f32x4 sa[2] = {};
#pragma unroll
    for (int cb = 0; cb < 2; cb++) {
      const ushort* kp = &Kb[(size_t)(kt + cb * 16 + lr) * HDIM + lg * 8];
      bf16x8 b0 = *(const bf16x8*)kp;
      bf16x8 b1 = *(const bf16x8*)(kp + 32);
      sa[cb] = mfma16(aq0, b0, sa[cb]);
      sa[cb] = mfma16(aq1, b1, sa[cb]);
    }
    float pv[2][4];
    float pm[4];
#pragma unroll
    for (int r = 0; r < 4; r++) {
      int row_abs = qw + lg * 4 + r;
      float best = -1e30f;
#pragma unroll
      for (int cb = 0; cb < 2; cb++) {
        int col = kt + cb * 16 + lr;
        float sv = sa[cb][r] * 0.125f;
        sv = (col <= row_abs) ? sv : -1e30f;
        pv[cb][r] = sv;
        best = fmaxf(best, sv);
      }
#pragma unroll
      for (int off = 1; off < 16; off <<= 1)
        best = fmaxf(best, __shfl_xor(best, off));
      pm[r] = best;
    }
#pragma unroll
    for (int r = 0; r < 4; r++) {
      float mn = fmaxf(m_run[r], pm[r]);
      float scale = __expf(m_run[r] - mn);
      m_run[r] = mn;
      float ps = 0.0f;
      ushort pb[2];
#pragma unroll
      for (int cb = 0; cb < 2; cb++) {
        float p = (pv[cb][r] <= -1e29f) ? 0.0f : __expf(pv[cb][r] - mn);
        ps += p;
        pb[cb] = f2bf(p);
      }
#pragma unroll
      for (int off = 1; off < 16; off <<= 1) ps += __shfl_xor(ps, off);
      l_run[r] = l_run[r] * scale + ps;
#pragma unroll
      for (int d = 0; d < 4; d++) o[d][r] *= scale;
      myp[(lg * 4 + r) * 32 + lr]      = pb[0];
      myp[(lg * 4 + r) * 32 + 16 + lr] = pb[1];
    }
    __syncthreads();
    bf16x8 pf = *(const bf16x8*)&myp[lr * 32 + lg * 8];
#pragma unroll
    for (int d = 0; d < 4; d++) {
      bf16x8 vf = *(const bf16x8*)&Vb[(size_t)(d * 16 + lr) * TSEQ + kt + lg * 8];
      o[d] = mfma16(pf, vf, o[d]);
    }
    __syncthreads();
  }

  int b = bh >> 4, h = bh & 15;
  int orow = b * TSEQ + qw + lg * 4;
#pragma unroll
  for (int r = 0; r < 4; r++) {
    float inv = 1.0f / l_run[r];
#pragma unroll
    for (int d = 0; d < 4; d++)
      O[(size_t)(orow + r) * DMODEL + h * 64 + d * 16 + lr] = f2bf(o[d][r] * inv);
  }
}

// ---------------- GEMM: C(M,N) = A(M,K) @ Bt(N,K)^T, bf16 in, f32 acc ------
// 128x128 tile, BK=32, 4 waves in 2x2, 16x16x32 MFMA (m97 structure).
// EPI: 0 bf16 out; 1 +resid f32 out; 2 +bias,gelu bf16 out; 3 +bias+resid f32.
template <int EPI>
__global__ __launch_bounds__(256)
void gemm_kernel(const ushort* __restrict__ A, const ushort* __restrict__ Bt,
                 void* __restrict__ Cout, const float* __restrict__ bias,
                 const float* __restrict__ resid, int M, int N, int K) {
  __shared__ ushort lA[128 * 32];
  __shared__ ushort lB[128 * 32];
  int tid = threadIdx.x;
  int lane = tid & 63, w = tid >> 6;
  int wm = w >> 1, wn = w & 1;
  int bm = blockIdx.x, bn = blockIdx.y;
  f32x4 acc[4][4] = {};

  const ushort* Ab = A + (size_t)bm * 128 * K;
  const ushort* Bb = Bt + (size_t)bn * 128 * K;
  int srow = tid >> 2, scol = (tid & 3) * 8;
  int lrow = lane & 15, lk = (lane >> 4) * 8;

  for (int k0 = 0; k0 < K; k0 += 32) {
    __syncthreads();
    gload_lds16(Ab + (size_t)srow * K + k0 + scol, &lA[tid * 8]);
    gload_lds16(Ab + (size_t)(srow + 64) * K + k0 + scol, &lA[(tid + 256) * 8]);
    gload_lds16(Bb + (size_t)srow * K + k0 + scol, &lB[tid * 8]);
    gload_lds16(Bb + (size_t)(srow + 64) * K + k0 + scol, &lB[(tid + 256) * 8]);
    __syncthreads();
    bf16x8 af[4], bfr[4];
#pragma unroll
    for (int m = 0; m < 4; m++)
      af[m] = *(const bf16x8*)&lA[(wm * 64 + m * 16 + lrow) * 32 + lk];
#pragma unroll
    for (int n = 0; n < 4; n++)
      bfr[n] = *(const bf16x8*)&lB[(wn * 64 + n * 16 + lrow) * 32 + lk];
#pragma unroll
    for (int m = 0; m < 4; m++)
#pragma unroll
      for (int n = 0; n < 4; n++)
        acc[m][n] = mfma16(af[m], bfr[n], acc[m][n]);
  }

#pragma unroll
  for (int m = 0; m < 4; m++) {
    int rbase = bm * 128 + wm * 64 + m * 16 + (lane >> 4) * 4;
#pragma unroll
    for (int n = 0; n < 4; n++) {
      int c = bn * 128 + wn * 64 + n * 16 + (lane & 15);
#pragma unroll
      for (int r = 0; r < 4; r++) {
        float v = acc[m][n][r];
        size_t idx = (size_t)(rbase + r) * N + c;
        if constexpr (EPI == 0) {
          ((ushort*)Cout)[idx] = f2bf(v);
        } else if constexpr (EPI == 1) {
          ((float*)Cout)[idx] = v + resid[idx];
        } else if constexpr (EPI == 2) {
          ((ushort*)Cout)[idx] = f2bf(gelu_f(v + bias[c]));
        } else {
          ((float*)Cout)[idx] = v + bias[c] + resid[idx];
        }
      }
    }
  }
}

// ---------------------------------------------------------------------------
extern "C" void kernel_launch(void* const* d_in, const int* in_sizes, int n_in,
                              void* d_out, int out_size, void* d_ws,
                              size_t ws_size, hipStream_t stream) {
  const float* x      = (const float*)d_in[0];
  const int* positions = (const int*)d_in[1];
  // d_in[2] = mask (implicit causal)
  const float* ln1_s  = (const float*)d_in[3];
  const float* ln1_b  = (const float*)d_in[4];
  const float* w_qkv  = (const float*)d_in[5];
  const float* w_o    = (const float*)d_in[6];
  const float* ln2_s  = (const float*)d_in[7];
  const float* ln2_b  = (const float*)d_in[8];
  const float* w1     = (const float*)d_in[9];
  const float* b1     = (const float*)d_in[10];
  const float* w2     = (const float*)d_in[11];
  const float* b2     = (const float*)d_in[12];
  float* out = (float*)d_out;

  char* ws = (char*)d_ws;
  size_t off = 0;
  auto nxt = [&](size_t bytes) {
    char* p = ws + off;
    off += (bytes + 255) & ~(size_t)255;
    return p;
  };
  ushort* wqkvT = (ushort*)nxt(3072ULL * 1024 * 2);
  ushort* woT   = (ushort*)nxt(1024ULL * 1024 * 2);
  ushort* w1T   = (ushort*)nxt(4096ULL * 1024 * 2);
  ushort* w2T   = (ushort*)nxt(1024ULL * 4096 * 2);
  ushort* h1    = (ushort*)nxt((size_t)M_ROWS * DMODEL * 2);
  ushort* qkv   = (ushort*)nxt((size_t)M_ROWS * 3072 * 2);
  ushort* Qb    = (ushort*)nxt(2ULL * NHEAD * TSEQ * HDIM * 2);
  ushort* Kb    = (ushort*)nxt(2ULL * NHEAD * TSEQ * HDIM * 2);
  ushort* VTb   = (ushort*)nxt(2ULL * NHEAD * TSEQ * HDIM * 2);
  ushort* attn  = (ushort*)nxt((size_t)M_ROWS * DMODEL * 2);
  float*  x2    = (float*)nxt((size_t)M_ROWS * DMODEL * 4);
  ushort* h2    = (ushort*)nxt((size_t)M_ROWS * DMODEL * 2);
  ushort* mid   = (ushort*)nxt((size_t)M_ROWS * 4096 * 2);
  float2* tab   = (float2*)nxt((size_t)TSEQ * 32 * 8);

  transpose_bf16<<<dim3(3072 / 32, 1024 / 32), 256, 0, stream>>>(w_qkv, wqkvT, 1024, 3072);
  transpose_bf16<<<dim3(1024 / 32, 1024 / 32), 256, 0, stream>>>(w_o, woT, 1024, 1024);
  transpose_bf16<<<dim3(4096 / 32, 1024 / 32), 256, 0, stream>>>(w1, w1T, 1024, 4096);
  transpose_bf16<<<dim3(1024 / 32, 4096 / 32), 256, 0, stream>>>(w2, w2T, 4096, 1024);
  rope_table<<<(TSEQ * 32) / 256, 256, 0, stream>>>(positions, tab);
  ln_kernel<<<M_ROWS, 256, 0, stream>>>(x, ln1_s, ln1_b, h1);
  gemm_kernel<0><<<dim3(32, 24), 256, 0, stream>>>(h1, wqkvT, qkv, nullptr, nullptr, 4096, 3072, 1024);
  rope_apply<<<(2 * TSEQ * NHEAD * 32) / 256, 256, 0, stream>>>(qkv, tab, Qb, Kb, VTb);
  attn_kernel<<<dim3(TSEQ / 64, 2 * NHEAD), 256, 0, stream>>>(Qb, Kb, VTb, attn);
  gemm_kernel<1><<<dim3(32, 8), 256, 0, stream>>>(attn, woT, x2, nullptr, x, 4096, 1024, 1024);
  ln_kernel<<<M_ROWS, 256, 0, stream>>>(x2, ln2_s, ln2_b, h2);
  gemm_kernel<2><<<dim3(32, 32), 256, 0, stream>>>(h2, w1T, mid, b1, nullptr, 4096, 4096, 1024);
  gemm_kernel<3><<<dim3(32, 8), 256, 0, stream>>>(mid, w2T, out, b2, x2, 4096, 1024, 4096);
}

// Round 2
// 492.521 us; speedup vs baseline: 1.0184x; 1.0184x over previous
//
#include <hip/hip_runtime.h>

// Decoder block: B=2 T=2048 D=1024 H=16 hd=64 HIDDEN=4096. All f32 in/out,
// bf16 MFMA internally (threshold is bf16-floor).
//
// Pipeline (all on `stream`):
//  1. transpose+cvt weights f32(K,N) -> bf16(N,K)      (4 launches)
//  2. rope cos/sin table (T x 32 f32x2)
//  3. LN1: x -> h1 bf16
//  4. GEMM qkv = h1 @ Wqkv             (EPI 0: plain bf16 out)
//  5. rope_apply: qkv -> Q,K (B,H,T,hd) and V^T (B,H,hd,T) bf16
//  6. attention (flash, causal) -> attn bf16 (M,D)
//  7. GEMM x2 = attn @ Wo + x          (EPI 1: +resid, f32 out)
//  8. LN2: x2 -> h2 bf16
//  9. GEMM mid = gelu(h2 @ W1 + b1)    (EPI 2: +bias,gelu, bf16 out)
// 10. GEMM out = mid @ W2 + b2 + x2    (EPI 3: +bias+resid, f32 out)

typedef __bf16 bf16_t;
typedef bf16_t bf16x8 __attribute__((ext_vector_type(8)));
typedef float f32x4 __attribute__((ext_vector_type(4)));

#define M_ROWS 4096   // B*T
#define DMODEL 1024
#define TSEQ   2048
#define NHEAD  16
#define HDIM   64

__device__ __forceinline__ ushort f2bf(float f) {
  union { float f; unsigned u; } v; v.f = f;
  unsigned r = (v.u + 0x7fffu + ((v.u >> 16) & 1u)) >> 16;
  return (ushort)r;
}
__device__ __forceinline__ float bf2f(ushort u) {
  union { unsigned u; float f; } v; v.u = ((unsigned)u) << 16;
  return v.f;
}
__device__ __forceinline__ void gload_lds16(const void* g, void* l) {
  __builtin_amdgcn_global_load_lds(
      (const __attribute__((address_space(1))) unsigned*)g,
      (__attribute__((address_space(3))) unsigned*)l, 16, 0, 0);
}
__device__ __forceinline__ f32x4 mfma16(bf16x8 a, bf16x8 b, f32x4 c) {
  return __builtin_amdgcn_mfma_f32_16x16x32_bf16(a, b, c, 0, 0, 0);
}
__device__ __forceinline__ float gelu_f(float x) {
  float y = 0.7978845608028654f * (x + 0.044715f * x * x * x);
  float e = __expf(2.0f * y);
  float t = 1.0f - 2.0f / (e + 1.0f);   // tanh(y), overflow-safe
  return 0.5f * x * (1.0f + t);
}

// ---------------- weight transpose + f32->bf16 -----------------------------
// src: (K,N) f32 row-major. dst: (N,K) bf16 row-major. grid (N/32, K/32).
__global__ __launch_bounds__(256)
void transpose_bf16(const float* __restrict__ src, ushort* __restrict__ dst,
                    int K, int N) {
  __shared__ float t[32][33];
  int n0 = blockIdx.x * 32, k0 = blockIdx.y * 32;
  int tx = threadIdx.x & 31, ty = threadIdx.x >> 5;  // ty in [0,8)
#pragma unroll
  for (int i = 0; i < 4; i++) {
    int k = ty + i * 8;
    t[k][tx] = src[(size_t)(k0 + k) * N + n0 + tx];
  }
  __syncthreads();
#pragma unroll
  for (int i = 0; i < 4; i++) {
    int nn = ty + i * 8;
    dst[(size_t)(n0 + nn) * K + k0 + tx] = f2bf(t[tx][nn]);
  }
}

// ---------------- layernorm (f32 in, bf16 out) -----------------------------
__global__ __launch_bounds__(256)
void ln_kernel(const float* __restrict__ x, const float* __restrict__ sc,
               const float* __restrict__ bi, ushort* __restrict__ out) {
  int row = blockIdx.x;
  int tid = threadIdx.x;
  const float4 v = *(const float4*)&x[(size_t)row * DMODEL + tid * 4];
  float s = v.x + v.y + v.z + v.w;
  float s2 = v.x * v.x + v.y * v.y + v.z * v.z + v.w * v.w;
#pragma unroll
  for (int off = 32; off > 0; off >>= 1) {
    s += __shfl_down(s, off);
    s2 += __shfl_down(s2, off);
  }
  __shared__ float red[8];
  int lane = tid & 63, w = tid >> 6;
  if (lane == 0) { red[w * 2] = s; red[w * 2 + 1] = s2; }
  __syncthreads();
  float S = red[0] + red[2] + red[4] + red[6];
  float S2 = red[1] + red[3] + red[5] + red[7];
  float mu = S * (1.0f / DMODEL);
  float var = S2 * (1.0f / DMODEL) - mu * mu;
  float rs = rsqrtf(var + 1e-6f);
  float4 scv = *(const float4*)&sc[tid * 4];
  float4 biv = *(const float4*)&bi[tid * 4];
  ushort4 o;
  o.x = f2bf((v.x - mu) * rs * scv.x + biv.x);
  o.y = f2bf((v.y - mu) * rs * scv.y + biv.y);
  o.z = f2bf((v.z - mu) * rs * scv.z + biv.z);
  o.w = f2bf((v.w - mu) * rs * scv.w + biv.w);
  *(ushort4*)&out[(size_t)row * DMODEL + tid * 4] = o;
}

// ---------------- rope table -----------------------------------------------
__global__ __launch_bounds__(256)
void rope_table(const int* __restrict__ positions, float2* __restrict__ tab) {
  int i = blockIdx.x * 256 + threadIdx.x;  // T*32
  int t = i >> 5, f = i & 31;
  float inv = __expf(-(float)f * (1.0f / 32.0f) * 9.210340371976184f);  // ln(10000)
  float a = (float)positions[t] * inv;
  tab[i] = make_float2(cosf(a), sinf(a));
}

// ---------------- rope apply + QKV reshape ---------------------------------
// qkv: (B*T, 3*D) bf16. Q,K: (B,H,T,hd). VT: (B,H,hd,T).
__global__ __launch_bounds__(256)
void rope_apply(const ushort* __restrict__ qkv, const float2* __restrict__ tab,
                ushort* __restrict__ Q, ushort* __restrict__ Kd,
                ushort* __restrict__ VT) {
  int i = blockIdx.x * 256 + threadIdx.x;  // B*T*H*32
  int f = i & 31;
  int h = (i >> 5) & 15;
  int t = (i >> 9) & 2047;
  int b = i >> 20;
  int row = b * TSEQ + t;
  const ushort* qr = qkv + (size_t)row * 3072;
  float2 cs = tab[t * 32 + f];
  float c = cs.x, s = cs.y;
  float q1 = bf2f(qr[h * 64 + f]),        q2 = bf2f(qr[h * 64 + 32 + f]);
  float k1 = bf2f(qr[1024 + h * 64 + f]), k2 = bf2f(qr[1024 + h * 64 + 32 + f]);
  float v1 = bf2f(qr[2048 + h * 64 + f]), v2 = bf2f(qr[2048 + h * 64 + 32 + f]);
  size_t bh = (size_t)(b * NHEAD + h);
  ushort* Qp = Q + bh * TSEQ * HDIM + (size_t)t * HDIM;
  ushort* Kp = Kd + bh * TSEQ * HDIM + (size_t)t * HDIM;
  Qp[f]      = f2bf(q1 * c - q2 * s);
  Qp[f + 32] = f2bf(q1 * s + q2 * c);
  Kp[f]      = f2bf(k1 * c - k2 * s);
  Kp[f + 32] = f2bf(k1 * s + k2 * c);
  ushort* Vp = VT + bh * HDIM * TSEQ;
  Vp[(size_t)f * TSEQ + t] = f2bf(v1);
  Vp[(size_t)(f + 32) * TSEQ + t] = f2bf(v2);
}

// ---------------- attention (flash, causal) --------------------------------
// grid (T/64, B*H), 256 thr = 4 fully-independent waves (no barriers).
// Wave w owns q-rows qb*64+w*16..+16; KVBLK=64 per iteration.
// P goes through a per-wave XOR-swizzled LDS tile (16x64 bf16) to convert
// the MFMA C-layout into the A-fragment layout for PV.
__global__ __launch_bounds__(256)
void attn_kernel(const ushort* __restrict__ Q, const ushort* __restrict__ Kd,
                 const ushort* __restrict__ VT, ushort* __restrict__ O) {
  int qb = blockIdx.x;
  int bh = blockIdx.y;
  int tid = threadIdx.x, lane = tid & 63, w = tid >> 6;
  int qw = qb * 64 + w * 16;
  const ushort* Qb = Q + (size_t)bh * TSEQ * HDIM;
  const ushort* Kb = Kd + (size_t)bh * TSEQ * HDIM;
  const ushort* Vb = VT + (size_t)bh * HDIM * TSEQ;

  __shared__ ushort lp[4][16 * 64];
  ushort* myp = lp[w];

  int lr = lane & 15, lg = lane >> 4;

  // Q fragments, pre-scaled by 1/sqrt(hd)=0.125 (exact in bf16: 2^-3)
  bf16x8 aq0 = *(const bf16x8*)&Qb[(size_t)(qw + lr) * HDIM + lg * 8];
  bf16x8 aq1 = *(const bf16x8*)&Qb[(size_t)(qw + lr) * HDIM + 32 + lg * 8];
#pragma unroll
  for (int j = 0; j < 8; j++) {
    aq0[j] = (bf16_t)((float)aq0[j] * 0.125f);
    aq1[j] = (bf16_t)((float)aq1[j] * 0.125f);
  }

  float m_run[4], l_run[4];
  f32x4 o[4] = {};
#pragma unroll
  for (int r = 0; r < 4; r++) { m_run[r] = -1e30f; l_run[r] = 0.0f; }

  int nt = qb + 1;  // 64-key tiles; uniform across waves of this block
  for (int it = 0; it < nt; ++it) {
    int kt = it * 64;
    bool diag = (it == nt - 1);

    // ---- load all K and V fragments for this 64-key tile up front ----
    bf16x8 kb0[4], kb1[4];
#pragma unroll
    for (int cb = 0; cb < 4; cb++) {
      const ushort* kp = &Kb[(size_t)(kt + cb * 16 + lr) * HDIM + lg * 8];
      kb0[cb] = *(const bf16x8*)kp;
      kb1[cb] = *(const bf16x8*)(kp + 32);
    }
    bf16x8 vf[4][2];
#pragma unroll
    for (int d = 0; d < 4; d++) {
      const ushort* vp = &Vb[(size_t)(d * 16 + lr) * TSEQ + kt + lg * 8];
      vf[d][0] = *(const bf16x8*)vp;
      vf[d][1] = *(const bf16x8*)(vp + 32);
    }

    // ---- QK^T: S (16q x 64k), C-layout row=q(lg*4+r) col=k(cb*16+lr) ----
    f32x4 sa[4] = {};
#pragma unroll
    for (int cb = 0; cb < 4; cb++) {
      sa[cb] = mfma16(aq0, kb0[cb], sa[cb]);
      sa[cb] = mfma16(aq1, kb1[cb], sa[cb]);
    }

    // ---- online softmax over 64 keys ----
#pragma unroll
    for (int r = 0; r < 4; r++) {
      int row_abs = qw + lg * 4 + r;
      float pv[4];
      float best = -1e30f;
#pragma unroll
      for (int cb = 0; cb < 4; cb++) {
        float sv = sa[cb][r];
        if (diag) {
          int col = kt + cb * 16 + lr;
          sv = (col <= row_abs) ? sv : -1e30f;
        }
        pv[cb] = sv;
        best = fmaxf(best, sv);
      }
#pragma unroll
      for (int off = 1; off < 16; off <<= 1)
        best = fmaxf(best, __shfl_xor(best, off));
      float mn = fmaxf(m_run[r], best);
      float scale = __expf(m_run[r] - mn);
      m_run[r] = mn;
      float ps = 0.0f;
      int row = lg * 4 + r;
      int sw = row & 7;
#pragma unroll
      for (int cb = 0; cb < 4; cb++) {
        float p = __expf(pv[cb] - mn);
        ps += p;
        int col = cb * 16 + lr;
        // XOR-swizzle 16B chunks within the row: chunk ^= row&7
        myp[row * 64 + (((col >> 3) ^ sw) << 3) + (col & 7)] = f2bf(p);
      }
#pragma unroll
      for (int off = 1; off < 16; off <<= 1) ps += __shfl_xor(ps, off);
      l_run[r] = l_run[r] * scale + ps;
#pragma unroll
      for (int d = 0; d < 4; d++) o[d][r] *= scale;
    }

    // ---- PV: O += P(16x64) @ V(64x64) ----
    bf16x8 pf0 = *(const bf16x8*)&myp[lr * 64 + (((0 * 4 + lg) ^ (lr & 7)) << 3)];
    bf16x8 pf1 = *(const bf16x8*)&myp[lr * 64 + (((1 * 4 + lg) ^ (lr & 7)) << 3)];
#pragma unroll
    for (int d = 0; d < 4; d++) {
      o[d] = mfma16(pf0, vf[d][0], o[d]);
      o[d] = mfma16(pf1, vf[d][1], o[d]);
    }
  }

  int b = bh >> 4, h = bh & 15;
  int orow = b * TSEQ + qw + lg * 4;
#pragma unroll
  for (int r = 0; r < 4; r++) {
    float inv = 1.0f / l_run[r];
#pragma unroll
    for (int d = 0; d < 4; d++)
      O[(size_t)(orow + r) * DMODEL + h * 64 + d * 16 + lr] = f2bf(o[d][r] * inv);
  }
}

// ---------------- GEMM: C(M,N) = A(M,K) @ Bt(N,K)^T, bf16 in, f32 acc ------
// 128x128 tile, BK=32, 4 waves in 2x2, 16x16x32 MFMA (m97 structure).
// EPI: 0 bf16 out; 1 +resid f32 out; 2 +bias,gelu bf16 out; 3 +bias+resid f32.
template <int EPI>
__global__ __launch_bounds__(256)
void gemm_kernel(const ushort* __restrict__ A, const ushort* __restrict__ Bt,
                 void* __restrict__ Cout, const float* __restrict__ bias,
                 const float* __restrict__ resid, int M, int N, int K) {
  __shared__ ushort lA[128 * 32];
  __shared__ ushort lB[128 * 32];
  int tid = threadIdx.x;
  int lane = tid & 63, w = tid >> 6;
  int wm = w >> 1, wn = w & 1;
  int bm = blockIdx.x, bn = blockIdx.y;
  f32x4 acc[4][4] = {};

  const ushort* Ab = A + (size_t)bm * 128 * K;
  const ushort* Bb = Bt + (size_t)bn * 128 * K;
  int srow = tid >> 2, scol = (tid & 3) * 8;
  int lrow = lane & 15, lk = (lane >> 4) * 8;

  for (int k0 = 0; k0 < K; k0 += 32) {
    __syncthreads();
    gload_lds16(Ab + (size_t)srow * K + k0 + scol, &lA[tid * 8]);
    gload_lds16(Ab + (size_t)(srow + 64) * K + k0 + scol, &lA[(tid + 256) * 8]);
    gload_lds16(Bb + (size_t)srow * K + k0 + scol, &lB[tid * 8]);
    gload_lds16(Bb + (size_t)(srow + 64) * K + k0 + scol, &lB[(tid + 256) * 8]);
    __syncthreads();
    bf16x8 af[4], bfr[4];
#pragma unroll
    for (int m = 0; m < 4; m++)
      af[m] = *(const bf16x8*)&lA[(wm * 64 + m * 16 + lrow) * 32 + lk];
#pragma unroll
    for (int n = 0; n < 4; n++)
      bfr[n] = *(const bf16x8*)&lB[(wn * 64 + n * 16 + lrow) * 32 + lk];
#pragma unroll
    for (int m = 0; m < 4; m++)
#pragma unroll
      for (int n = 0; n < 4; n++)
        acc[m][n] = mfma16(af[m], bfr[n], acc[m][n]);
  }

#pragma unroll
  for (int m = 0; m < 4; m++) {
    int rbase = bm * 128 + wm * 64 + m * 16 + (lane >> 4) * 4;
#pragma unroll
    for (int n = 0; n < 4; n++) {
      int c = bn * 128 + wn * 64 + n * 16 + (lane & 15);
#pragma unroll
      for (int r = 0; r < 4; r++) {
        float v = acc[m][n][r];
        size_t idx = (size_t)(rbase + r) * N + c;
        if constexpr (EPI == 0) {
          ((ushort*)Cout)[idx] = f2bf(v);
        } else if constexpr (EPI == 1) {
          ((float*)Cout)[idx] = v + resid[idx];
        } else if constexpr (EPI == 2) {
          ((ushort*)Cout)[idx] = f2bf(gelu_f(v + bias[c]));
        } else {
          ((float*)Cout)[idx] = v + bias[c] + resid[idx];
        }
      }
    }
  }
}

// ---------------------------------------------------------------------------
extern "C" void kernel_launch(void* const* d_in, const int* in_sizes, int n_in,
                              void* d_out, int out_size, void* d_ws,
                              size_t ws_size, hipStream_t stream) {
  const float* x      = (const float*)d_in[0];
  const int* positions = (const int*)d_in[1];
  // d_in[2] = mask (implicit causal)
  const float* ln1_s  = (const float*)d_in[3];
  const float* ln1_b  = (const float*)d_in[4];
  const float* w_qkv  = (const float*)d_in[5];
  const float* w_o    = (const float*)d_in[6];
  const float* ln2_s  = (const float*)d_in[7];
  const float* ln2_b  = (const float*)d_in[8];
  const float* w1     = (const float*)d_in[9];
  const float* b1     = (const float*)d_in[10];
  const float* w2     = (const float*)d_in[11];
  const float* b2     = (const float*)d_in[12];
  float* out = (float*)d_out;

  char* ws = (char*)d_ws;
  size_t off = 0;
  auto nxt = [&](size_t bytes) {
    char* p = ws + off;
    off += (bytes + 255) & ~(size_t)255;
    return p;
  };
  ushort* wqkvT = (ushort*)nxt(3072ULL * 1024 * 2);
  ushort* woT   = (ushort*)nxt(1024ULL * 1024 * 2);
  ushort* w1T   = (ushort*)nxt(4096ULL * 1024 * 2);
  ushort* w2T   = (ushort*)nxt(1024ULL * 4096 * 2);
  ushort* h1    = (ushort*)nxt((size_t)M_ROWS * DMODEL * 2);
  ushort* qkv   = (ushort*)nxt((size_t)M_ROWS * 3072 * 2);
  ushort* Qb    = (ushort*)nxt(2ULL * NHEAD * TSEQ * HDIM * 2);
  ushort* Kb    = (ushort*)nxt(2ULL * NHEAD * TSEQ * HDIM * 2);
  ushort* VTb   = (ushort*)nxt(2ULL * NHEAD * TSEQ * HDIM * 2);
  ushort* attn  = (ushort*)nxt((size_t)M_ROWS * DMODEL * 2);
  float*  x2    = (float*)nxt((size_t)M_ROWS * DMODEL * 4);
  ushort* h2    = (ushort*)nxt((size_t)M_ROWS * DMODEL * 2);
  ushort* mid   = (ushort*)nxt((size_t)M_ROWS * 4096 * 2);
  float2* tab   = (float2*)nxt((size_t)TSEQ * 32 * 8);

  transpose_bf16<<<dim3(3072 / 32, 1024 / 32), 256, 0, stream>>>(w_qkv, wqkvT, 1024, 3072);
  transpose_bf16<<<dim3(1024 / 32, 1024 / 32), 256, 0, stream>>>(w_o, woT, 1024, 1024);
  transpose_bf16<<<dim3(4096 / 32, 1024 / 32), 256, 0, stream>>>(w1, w1T, 1024, 4096);
  transpose_bf16<<<dim3(1024 / 32, 4096 / 32), 256, 0, stream>>>(w2, w2T, 4096, 1024);
  rope_table<<<(TSEQ * 32) / 256, 256, 0, stream>>>(positions, tab);
  ln_kernel<<<M_ROWS, 256, 0, stream>>>(x, ln1_s, ln1_b, h1);
  gemm_kernel<0><<<dim3(32, 24), 256, 0, stream>>>(h1, wqkvT, qkv, nullptr, nullptr, 4096, 3072, 1024);
  rope_apply<<<(2 * TSEQ * NHEAD * 32) / 256, 256, 0, stream>>>(qkv, tab, Qb, Kb, VTb);
  attn_kernel<<<dim3(TSEQ / 64, 2 * NHEAD), 256, 0, stream>>>(Qb, Kb, VTb, attn);
  gemm_kernel<1><<<dim3(32, 8), 256, 0, stream>>>(attn, woT, x2, nullptr, x, 4096, 1024, 1024);
  ln_kernel<<<M_ROWS, 256, 0, stream>>>(x2, ln2_s, ln2_b, h2);
  gemm_kernel<2><<<dim3(32, 32), 256, 0, stream>>>(h2, w1T, mid, b1, nullptr, 4096, 4096, 1024);
  gemm_kernel<3><<<dim3(32, 8), 256, 0, stream>>>(mid, w2T, out, b2, x2, 4096, 1024, 4096);
}

// Round 3
// 391.102 us; speedup vs baseline: 1.2825x; 1.2593x over previous
//
#include <hip/hip_runtime.h>

// Decoder block: B=2 T=2048 D=1024 H=16 hd=64 HIDDEN=4096. All f32 in/out,
// bf16 MFMA internally (threshold is bf16-floor).

typedef __bf16 bf16_t;
typedef bf16_t bf16x8 __attribute__((ext_vector_type(8)));
typedef float f32x4 __attribute__((ext_vector_type(4)));

#define M_ROWS 4096   // B*T
#define DMODEL 1024
#define TSEQ   2048
#define NHEAD  16
#define HDIM   64

__device__ __forceinline__ ushort f2bf(float f) {
  union { float f; unsigned u; } v; v.f = f;
  unsigned r = (v.u + 0x7fffu + ((v.u >> 16) & 1u)) >> 16;
  return (ushort)r;
}
__device__ __forceinline__ float bf2f(ushort u) {
  union { unsigned u; float f; } v; v.u = ((unsigned)u) << 16;
  return v.f;
}
__device__ __forceinline__ void gload_lds16(const void* g, void* l) {
  __builtin_amdgcn_global_load_lds(
      (const __attribute__((address_space(1))) unsigned*)g,
      (__attribute__((address_space(3))) unsigned*)l, 16, 0, 0);
}
__device__ __forceinline__ f32x4 mfma16(bf16x8 a, bf16x8 b, f32x4 c) {
  return __builtin_amdgcn_mfma_f32_16x16x32_bf16(a, b, c, 0, 0, 0);
}
__device__ __forceinline__ float gelu_f(float x) {
  float y = 0.7978845608028654f * (x + 0.044715f * x * x * x);
  float e = __expf(2.0f * y);
  float t = 1.0f - 2.0f / (e + 1.0f);   // tanh(y), overflow-safe
  return 0.5f * x * (1.0f + t);
}

// ---------------- weight transpose + f32->bf16 -----------------------------
__global__ __launch_bounds__(256)
void transpose_bf16(const float* __restrict__ src, ushort* __restrict__ dst,
                    int K, int N) {
  __shared__ float t[32][33];
  int n0 = blockIdx.x * 32, k0 = blockIdx.y * 32;
  int tx = threadIdx.x & 31, ty = threadIdx.x >> 5;
#pragma unroll
  for (int i = 0; i < 4; i++) {
    int k = ty + i * 8;
    t[k][tx] = src[(size_t)(k0 + k) * N + n0 + tx];
  }
  __syncthreads();
#pragma unroll
  for (int i = 0; i < 4; i++) {
    int nn = ty + i * 8;
    dst[(size_t)(n0 + nn) * K + k0 + tx] = f2bf(t[tx][nn]);
  }
}

// ---------------- layernorm (f32 in, bf16 out) -----------------------------
__global__ __launch_bounds__(256)
void ln_kernel(const float* __restrict__ x, const float* __restrict__ sc,
               const float* __restrict__ bi, ushort* __restrict__ out) {
  int row = blockIdx.x;
  int tid = threadIdx.x;
  const float4 v = *(const float4*)&x[(size_t)row * DMODEL + tid * 4];
  float s = v.x + v.y + v.z + v.w;
  float s2 = v.x * v.x + v.y * v.y + v.z * v.z + v.w * v.w;
#pragma unroll
  for (int off = 32; off > 0; off >>= 1) {
    s += __shfl_down(s, off);
    s2 += __shfl_down(s2, off);
  }
  __shared__ float red[8];
  int lane = tid & 63, w = tid >> 6;
  if (lane == 0) { red[w * 2] = s; red[w * 2 + 1] = s2; }
  __syncthreads();
  float S = red[0] + red[2] + red[4] + red[6];
  float S2 = red[1] + red[3] + red[5] + red[7];
  float mu = S * (1.0f / DMODEL);
  float var = S2 * (1.0f / DMODEL) - mu * mu;
  float rs = rsqrtf(var + 1e-6f);
  float4 scv = *(const float4*)&sc[tid * 4];
  float4 biv = *(const float4*)&bi[tid * 4];
  ushort4 o;
  o.x = f2bf((v.x - mu) * rs * scv.x + biv.x);
  o.y = f2bf((v.y - mu) * rs * scv.y + biv.y);
  o.z = f2bf((v.z - mu) * rs * scv.z + biv.z);
  o.w = f2bf((v.w - mu) * rs * scv.w + biv.w);
  *(ushort4*)&out[(size_t)row * DMODEL + tid * 4] = o;
}

// ---------------- rope table -----------------------------------------------
__global__ __launch_bounds__(256)
void rope_table(const int* __restrict__ positions, float2* __restrict__ tab) {
  int i = blockIdx.x * 256 + threadIdx.x;  // T*32
  int t = i >> 5, f = i & 31;
  float inv = __expf(-(float)f * (1.0f / 32.0f) * 9.210340371976184f);
  float a = (float)positions[t] * inv;
  tab[i] = make_float2(cosf(a), sinf(a));
}

// ---------------- rope apply + QKV reshape ---------------------------------
__global__ __launch_bounds__(256)
void rope_apply(const ushort* __restrict__ qkv, const float2* __restrict__ tab,
                ushort* __restrict__ Q, ushort* __restrict__ Kd,
                ushort* __restrict__ VT) {
  int i = blockIdx.x * 256 + threadIdx.x;  // B*T*H*32
  int f = i & 31;
  int h = (i >> 5) & 15;
  int t = (i >> 9) & 2047;
  int b = i >> 20;
  int row = b * TSEQ + t;
  const ushort* qr = qkv + (size_t)row * 3072;
  float2 cs = tab[t * 32 + f];
  float c = cs.x, s = cs.y;
  float q1 = bf2f(qr[h * 64 + f]),        q2 = bf2f(qr[h * 64 + 32 + f]);
  float k1 = bf2f(qr[1024 + h * 64 + f]), k2 = bf2f(qr[1024 + h * 64 + 32 + f]);
  float v1 = bf2f(qr[2048 + h * 64 + f]), v2 = bf2f(qr[2048 + h * 64 + 32 + f]);
  size_t bh = (size_t)(b * NHEAD + h);
  ushort* Qp = Q + bh * TSEQ * HDIM + (size_t)t * HDIM;
  ushort* Kp = Kd + bh * TSEQ * HDIM + (size_t)t * HDIM;
  Qp[f]      = f2bf(q1 * c - q2 * s);
  Qp[f + 32] = f2bf(q1 * s + q2 * c);
  Kp[f]      = f2bf(k1 * c - k2 * s);
  Kp[f + 32] = f2bf(k1 * s + k2 * c);
  ushort* Vp = VT + bh * HDIM * TSEQ;
  Vp[(size_t)f * TSEQ + t] = f2bf(v1);
  Vp[(size_t)(f + 32) * TSEQ + t] = f2bf(v2);
}

// ---------------- attention (flash, causal, swapped-QK^T) ------------------
// grid (32 bh, 128 q-tiles) longest-first; 64 thr = 1 wave; 16 q-rows/wave.
// S^T = mfma(K,Q): lane holds 16 scores (k-major) of q-row lr -> in-register
// softmax with 2 shfl_xor per reduce. P->LDS (c8^lr swizzle) -> PV A-frags.
// K double-buffered in regs (prefetch next tile under softmax/PV).
__global__ __launch_bounds__(64)
void attn_kernel(const ushort* __restrict__ Q, const ushort* __restrict__ Kd,
                 const ushort* __restrict__ VT, ushort* __restrict__ O) {
  int bh = blockIdx.x;
  int mt = 127 - (int)blockIdx.y;   // longest-first
  int qw = mt * 16;
  int nt = (mt >> 2) + 1;           // 64-key tiles
  int lane = threadIdx.x & 63;
  int lr = lane & 15, lg = lane >> 4;
  int q_abs = qw + lr;              // this lane's q-row (softmax space)

  const ushort* Qb = Q + (size_t)bh * TSEQ * HDIM;
  const ushort* Kb = Kd + (size_t)bh * TSEQ * HDIM;
  const ushort* Vb = VT + (size_t)bh * HDIM * TSEQ;

  __shared__ ushort pt[16 * 64];

  // Q fragments, pre-scaled by 1/sqrt(hd)=0.125 (exact in bf16)
  bf16x8 aq0 = *(const bf16x8*)&Qb[(size_t)q_abs * HDIM + lg * 8];
  bf16x8 aq1 = *(const bf16x8*)&Qb[(size_t)q_abs * HDIM + 32 + lg * 8];
#pragma unroll
  for (int j = 0; j < 8; j++) {
    aq0[j] = (bf16_t)((float)aq0[j] * 0.125f);
    aq1[j] = (bf16_t)((float)aq1[j] * 0.125f);
  }

  float m_run = -1e30f, l_run = 0.0f;   // per-lane: stats of q-row lr
  f32x4 o[4] = {};

  bf16x8 kA0[4], kA1[4], kB0[4], kB1[4];
#pragma unroll
  for (int cb = 0; cb < 4; cb++) {       // prologue: K tile 0
    const ushort* kp = &Kb[(size_t)(cb * 16 + lr) * HDIM + lg * 8];
    kA0[cb] = *(const bf16x8*)kp;
    kA1[cb] = *(const bf16x8*)(kp + 32);
  }

#define ATTN_BODY(KC0, KC1, KN0, KN1)                                         \
  {                                                                           \
    int kt = it * 64;                                                         \
    bool diag = (it == nt - 1);                                               \
    bf16x8 vf0[4], vf1[4];                                                    \
    _Pragma("unroll")                                                         \
    for (int d = 0; d < 4; d++) {                                             \
      const ushort* vp = &Vb[(size_t)(d * 16 + lr) * TSEQ + kt + lg * 8];     \
      vf0[d] = *(const bf16x8*)vp;                                            \
      vf1[d] = *(const bf16x8*)(vp + 32);                                     \
    }                                                                         \
    f32x4 sa[4];                                                              \
    _Pragma("unroll")                                                         \
    for (int cb = 0; cb < 4; cb++) {                                          \
      f32x4 z = {};                                                           \
      z = mfma16(KC0[cb], aq0, z);                                            \
      sa[cb] = mfma16(KC1[cb], aq1, z);                                       \
    }                                                                         \
    if (it + 1 < nt) {                                                        \
      int kt2 = kt + 64;                                                      \
      _Pragma("unroll")                                                       \
      for (int cb = 0; cb < 4; cb++) {                                        \
        const ushort* kp = &Kb[(size_t)(kt2 + cb * 16 + lr) * HDIM + lg * 8]; \
        KN0[cb] = *(const bf16x8*)kp;                                         \
        KN1[cb] = *(const bf16x8*)(kp + 32);                                  \
      }                                                                       \
    }                                                                         \
    /* in-lane softmax: lane holds S[k=kt+cb*16+lg*4+r][q=lr] */              \
    float mloc = -1e30f;                                                      \
    if (diag) {                                                               \
      _Pragma("unroll")                                                       \
      for (int cb = 0; cb < 4; cb++)                                          \
        _Pragma("unroll")                                                     \
        for (int r = 0; r < 4; r++) {                                         \
          int k = kt + cb * 16 + lg * 4 + r;                                  \
          if (k > q_abs) sa[cb][r] = -1e30f;                                  \
          mloc = fmaxf(mloc, sa[cb][r]);                                      \
        }                                                                     \
    } else {                                                                  \
      _Pragma("unroll")                                                       \
      for (int cb = 0; cb < 4; cb++)                                          \
        _Pragma("unroll")                                                     \
        for (int r = 0; r < 4; r++) mloc = fmaxf(mloc, sa[cb][r]);            \
    }                                                                         \
    mloc = fmaxf(mloc, __shfl_xor(mloc, 16, 64));                             \
    mloc = fmaxf(mloc, __shfl_xor(mloc, 32, 64));                             \
    float mn = fmaxf(m_run, mloc);                                            \
    float rescale = __expf(m_run - mn);                                       \
    m_run = mn;                                                               \
    float ps = 0.0f;                                                          \
    ushort4 pk[4];                                                            \
    _Pragma("unroll")                                                         \
    for (int cb = 0; cb < 4; cb++) {                                          \
      float p0 = __expf(sa[cb][0] - mn);                                      \
      float p1 = __expf(sa[cb][1] - mn);                                      \
      float p2 = __expf(sa[cb][2] - mn);                                      \
      float p3 = __expf(sa[cb][3] - mn);                                      \
      ps += (p0 + p1) + (p2 + p3);                                            \
      pk[cb].x = f2bf(p0); pk[cb].y = f2bf(p1);                               \
      pk[cb].z = f2bf(p2); pk[cb].w = f2bf(p3);                               \
    }                                                                         \
    ps += __shfl_xor(ps, 16, 64);                                             \
    ps += __shfl_xor(ps, 32, 64);                                             \
    l_run = l_run * rescale + ps;                                             \
    /* store P (swizzled) */                                                  \
    _Pragma("unroll")                                                         \
    for (int cb = 0; cb < 4; cb++)                                            \
      *(ushort4*)&pt[lr * 64 + (((cb * 4 + lg) ^ lr) << 2)] = pk[cb];         \
    /* rescale o by per-q factor (broadcast lr-space -> C-layout rows) */     \
    _Pragma("unroll")                                                         \
    for (int r = 0; r < 4; r++) {                                             \
      float sc = __shfl(rescale, lg * 4 + r, 64);                             \
      _Pragma("unroll")                                                       \
      for (int d = 0; d < 4; d++) o[d][r] *= sc;                              \
    }                                                                         \
    /* read PV A-frags */                                                     \
    union U8 { ushort4 h[2]; bf16x8 v; };                                     \
    U8 t0, t1;                                                                \
    t0.h[0] = *(const ushort4*)&pt[lr * 64 + (((lg * 2    ) ^ lr) << 2)];     \
    t0.h[1] = *(const ushort4*)&pt[lr * 64 + (((lg * 2 + 1) ^ lr) << 2)];     \
    t1.h[0] = *(const ushort4*)&pt[lr * 64 + (((8 + lg * 2    ) ^ lr) << 2)]; \
    t1.h[1] = *(const ushort4*)&pt[lr * 64 + (((8 + lg * 2 + 1) ^ lr) << 2)]; \
    _Pragma("unroll")                                                         \
    for (int d = 0; d < 4; d++) {                                             \
      o[d] = mfma16(t0.v, vf0[d], o[d]);                                      \
      o[d] = mfma16(t1.v, vf1[d], o[d]);                                      \
    }                                                                         \
  }

  for (int it = 0; it < nt; ++it) {
    if (it & 1) {
      ATTN_BODY(kB0, kB1, kA0, kA1)
    } else {
      ATTN_BODY(kA0, kA1, kB0, kB1)
    }
  }
#undef ATTN_BODY

  int b = bh >> 4, h = bh & 15;
  float linv = 1.0f / l_run;
  int orow = b * TSEQ + qw + lg * 4;
#pragma unroll
  for (int r = 0; r < 4; r++) {
    float inv = __shfl(linv, lg * 4 + r, 64);
#pragma unroll
    for (int d = 0; d < 4; d++)
      O[(size_t)(orow + r) * DMODEL + h * 64 + d * 16 + lr] = f2bf(o[d][r] * inv);
  }
}

// ---------------- GEMM: C(M,N) = A(M,K) @ Bt(N,K)^T, bf16 in, f32 acc ------
// 128x128 tile, BK=32, 4 waves in 2x2, 16x16x32 MFMA (m97 structure).
template <int EPI>
__global__ __launch_bounds__(256)
void gemm_kernel(const ushort* __restrict__ A, const ushort* __restrict__ Bt,
                 void* __restrict__ Cout, const float* __restrict__ bias,
                 const float* __restrict__ resid, int M, int N, int K) {
  __shared__ ushort lA[128 * 32];
  __shared__ ushort lB[128 * 32];
  int tid = threadIdx.x;
  int lane = tid & 63, w = tid >> 6;
  int wm = w >> 1, wn = w & 1;
  int bm = blockIdx.x, bn = blockIdx.y;
  f32x4 acc[4][4] = {};

  const ushort* Ab = A + (size_t)bm * 128 * K;
  const ushort* Bb = Bt + (size_t)bn * 128 * K;
  int srow = tid >> 2, scol = (tid & 3) * 8;
  int lrow = lane & 15, lk = (lane >> 4) * 8;

  for (int k0 = 0; k0 < K; k0 += 32) {
    __syncthreads();
    gload_lds16(Ab + (size_t)srow * K + k0 + scol, &lA[tid * 8]);
    gload_lds16(Ab + (size_t)(srow + 64) * K + k0 + scol, &lA[(tid + 256) * 8]);
    gload_lds16(Bb + (size_t)srow * K + k0 + scol, &lB[tid * 8]);
    gload_lds16(Bb + (size_t)(srow + 64) * K + k0 + scol, &lB[(tid + 256) * 8]);
    __syncthreads();
    bf16x8 af[4], bfr[4];
#pragma unroll
    for (int m = 0; m < 4; m++)
      af[m] = *(const bf16x8*)&lA[(wm * 64 + m * 16 + lrow) * 32 + lk];
#pragma unroll
    for (int n = 0; n < 4; n++)
      bfr[n] = *(const bf16x8*)&lB[(wn * 64 + n * 16 + lrow) * 32 + lk];
#pragma unroll
    for (int m = 0; m < 4; m++)
#pragma unroll
      for (int n = 0; n < 4; n++)
        acc[m][n] = mfma16(af[m], bfr[n], acc[m][n]);
  }

#pragma unroll
  for (int m = 0; m < 4; m++) {
    int rbase = bm * 128 + wm * 64 + m * 16 + (lane >> 4) * 4;
#pragma unroll
    for (int n = 0; n < 4; n++) {
      int c = bn * 128 + wn * 64 + n * 16 + (lane & 15);
#pragma unroll
      for (int r = 0; r < 4; r++) {
        float v = acc[m][n][r];
        size_t idx = (size_t)(rbase + r) * N + c;
        if constexpr (EPI == 0) {
          ((ushort*)Cout)[idx] = f2bf(v);
        } else if constexpr (EPI == 1) {
          ((float*)Cout)[idx] = v + resid[idx];
        } else if constexpr (EPI == 2) {
          ((ushort*)Cout)[idx] = f2bf(gelu_f(v + bias[c]));
        } else {
          ((float*)Cout)[idx] = v + bias[c] + resid[idx];
        }
      }
    }
  }
}

// ---------------------------------------------------------------------------
extern "C" void kernel_launch(void* const* d_in, const int* in_sizes, int n_in,
                              void* d_out, int out_size, void* d_ws,
                              size_t ws_size, hipStream_t stream) {
  const float* x      = (const float*)d_in[0];
  const int* positions = (const int*)d_in[1];
  const float* ln1_s  = (const float*)d_in[3];
  const float* ln1_b  = (const float*)d_in[4];
  const float* w_qkv  = (const float*)d_in[5];
  const float* w_o    = (const float*)d_in[6];
  const float* ln2_s  = (const float*)d_in[7];
  const float* ln2_b  = (const float*)d_in[8];
  const float* w1     = (const float*)d_in[9];
  const float* b1     = (const float*)d_in[10];
  const float* w2     = (const float*)d_in[11];
  const float* b2     = (const float*)d_in[12];
  float* out = (float*)d_out;

  char* ws = (char*)d_ws;
  size_t off = 0;
  auto nxt = [&](size_t bytes) {
    char* p = ws + off;
    off += (bytes + 255) & ~(size_t)255;
    return p;
  };
  ushort* wqkvT = (ushort*)nxt(3072ULL * 1024 * 2);
  ushort* woT   = (ushort*)nxt(1024ULL * 1024 * 2);
  ushort* w1T   = (ushort*)nxt(4096ULL * 1024 * 2);
  ushort* w2T   = (ushort*)nxt(1024ULL * 4096 * 2);
  ushort* h1    = (ushort*)nxt((size_t)M_ROWS * DMODEL * 2);
  ushort* qkv   = (ushort*)nxt((size_t)M_ROWS * 3072 * 2);
  ushort* Qb    = (ushort*)nxt(2ULL * NHEAD * TSEQ * HDIM * 2);
  ushort* Kb    = (ushort*)nxt(2ULL * NHEAD * TSEQ * HDIM * 2);
  ushort* VTb   = (ushort*)nxt(2ULL * NHEAD * TSEQ * HDIM * 2);
  ushort* attn  = (ushort*)nxt((size_t)M_ROWS * DMODEL * 2);
  float*  x2    = (float*)nxt((size_t)M_ROWS * DMODEL * 4);
  ushort* h2    = (ushort*)nxt((size_t)M_ROWS * DMODEL * 2);
  ushort* mid   = (ushort*)nxt((size_t)M_ROWS * 4096 * 2);
  float2* tab   = (float2*)nxt((size_t)TSEQ * 32 * 8);

  transpose_bf16<<<dim3(3072 / 32, 1024 / 32), 256, 0, stream>>>(w_qkv, wqkvT, 1024, 3072);
  transpose_bf16<<<dim3(1024 / 32, 1024 / 32), 256, 0, stream>>>(w_o, woT, 1024, 1024);
  transpose_bf16<<<dim3(4096 / 32, 1024 / 32), 256, 0, stream>>>(w1, w1T, 1024, 4096);
  transpose_bf16<<<dim3(1024 / 32, 4096 / 32), 256, 0, stream>>>(w2, w2T, 4096, 1024);
  rope_table<<<(TSEQ * 32) / 256, 256, 0, stream>>>(positions, tab);
  ln_kernel<<<M_ROWS, 256, 0, stream>>>(x, ln1_s, ln1_b, h1);
  gemm_kernel<0><<<dim3(32, 24), 256, 0, stream>>>(h1, wqkvT, qkv, nullptr, nullptr, 4096, 3072, 1024);
  rope_apply<<<(2 * TSEQ * NHEAD * 32) / 256, 256, 0, stream>>>(qkv, tab, Qb, Kb, VTb);
  attn_kernel<<<dim3(32, 128), 64, 0, stream>>>(Qb, Kb, VTb, attn);
  gemm_kernel<1><<<dim3(32, 8), 256, 0, stream>>>(attn, woT, x2, nullptr, x, 4096, 1024, 1024);
  ln_kernel<<<M_ROWS, 256, 0, stream>>>(x2, ln2_s, ln2_b, h2);
  gemm_kernel<2><<<dim3(32, 32), 256, 0, stream>>>(h2, w1T, mid, b1, nullptr, 4096, 4096, 1024);
  gemm_kernel<3><<<dim3(32, 8), 256, 0, stream>>>(mid, w2T, out, b2, x2, 4096, 1024, 4096);
}

// Round 4
// 376.596 us; speedup vs baseline: 1.3319x; 1.0385x over previous
//
#include <hip/hip_runtime.h>

// Decoder block: B=2 T=2048 D=1024 H=16 hd=64 HIDDEN=4096. All f32 in/out,
// bf16 MFMA internally (threshold is bf16-floor).

typedef __bf16 bf16_t;
typedef bf16_t bf16x8 __attribute__((ext_vector_type(8)));
typedef float f32x4 __attribute__((ext_vector_type(4)));

#define M_ROWS 4096   // B*T
#define DMODEL 1024
#define TSEQ   2048
#define NHEAD  16
#define HDIM   64

__device__ __forceinline__ ushort f2bf(float f) {
  union { float f; unsigned u; } v; v.f = f;
  unsigned r = (v.u + 0x7fffu + ((v.u >> 16) & 1u)) >> 16;
  return (ushort)r;
}
__device__ __forceinline__ float bf2f(ushort u) {
  union { unsigned u; float f; } v; v.u = ((unsigned)u) << 16;
  return v.f;
}
__device__ __forceinline__ unsigned cvt_pk_bf16(float a, float b) {
  unsigned r;
  asm("v_cvt_pk_bf16_f32 %0, %1, %2" : "=v"(r) : "v"(a), "v"(b));
  return r;
}
__device__ __forceinline__ void gload_lds16(const void* g, void* l) {
  __builtin_amdgcn_global_load_lds(
      (const __attribute__((address_space(1))) unsigned*)g,
      (__attribute__((address_space(3))) unsigned*)l, 16, 0, 0);
}
__device__ __forceinline__ f32x4 mfma16(bf16x8 a, bf16x8 b, f32x4 c) {
  return __builtin_amdgcn_mfma_f32_16x16x32_bf16(a, b, c, 0, 0, 0);
}
__device__ __forceinline__ float gelu_f(float x) {
  float y = 0.7978845608028654f * (x + 0.044715f * x * x * x);
  float e = __expf(2.0f * y);
  float t = 1.0f - 2.0f / (e + 1.0f);   // tanh(y), overflow-safe
  return 0.5f * x * (1.0f + t);
}

// ---------------- weight transpose + f32->bf16 -----------------------------
__global__ __launch_bounds__(256)
void transpose_bf16(const float* __restrict__ src, ushort* __restrict__ dst,
                    int K, int N) {
  __shared__ float t[32][33];
  int n0 = blockIdx.x * 32, k0 = blockIdx.y * 32;
  int tx = threadIdx.x & 31, ty = threadIdx.x >> 5;
#pragma unroll
  for (int i = 0; i < 4; i++) {
    int k = ty + i * 8;
    t[k][tx] = src[(size_t)(k0 + k) * N + n0 + tx];
  }
  __syncthreads();
#pragma unroll
  for (int i = 0; i < 4; i++) {
    int nn = ty + i * 8;
    dst[(size_t)(n0 + nn) * K + k0 + tx] = f2bf(t[tx][nn]);
  }
}

// ---------------- layernorm (f32 in, bf16 out) -----------------------------
__global__ __launch_bounds__(256)
void ln_kernel(const float* __restrict__ x, const float* __restrict__ sc,
               const float* __restrict__ bi, ushort* __restrict__ out) {
  int row = blockIdx.x;
  int tid = threadIdx.x;
  const float4 v = *(const float4*)&x[(size_t)row * DMODEL + tid * 4];
  float s = v.x + v.y + v.z + v.w;
  float s2 = v.x * v.x + v.y * v.y + v.z * v.z + v.w * v.w;
#pragma unroll
  for (int off = 32; off > 0; off >>= 1) {
    s += __shfl_down(s, off);
    s2 += __shfl_down(s2, off);
  }
  __shared__ float red[8];
  int lane = tid & 63, w = tid >> 6;
  if (lane == 0) { red[w * 2] = s; red[w * 2 + 1] = s2; }
  __syncthreads();
  float S = red[0] + red[2] + red[4] + red[6];
  float S2 = red[1] + red[3] + red[5] + red[7];
  float mu = S * (1.0f / DMODEL);
  float var = S2 * (1.0f / DMODEL) - mu * mu;
  float rs = rsqrtf(var + 1e-6f);
  float4 scv = *(const float4*)&sc[tid * 4];
  float4 biv = *(const float4*)&bi[tid * 4];
  ushort4 o;
  o.x = f2bf((v.x - mu) * rs * scv.x + biv.x);
  o.y = f2bf((v.y - mu) * rs * scv.y + biv.y);
  o.z = f2bf((v.z - mu) * rs * scv.z + biv.z);
  o.w = f2bf((v.w - mu) * rs * scv.w + biv.w);
  *(ushort4*)&out[(size_t)row * DMODEL + tid * 4] = o;
}

// ---------------- rope table -----------------------------------------------
__global__ __launch_bounds__(256)
void rope_table(const int* __restrict__ positions, float2* __restrict__ tab) {
  int i = blockIdx.x * 256 + threadIdx.x;  // T*32
  int t = i >> 5, f = i & 31;
  float inv = __expf(-(float)f * (1.0f / 32.0f) * 9.210340371976184f);
  float a = (float)positions[t] * inv;
  tab[i] = make_float2(cosf(a), sinf(a));
}

// ---------------- rope apply + QKV reshape ---------------------------------
// grid (T/64, B*H), 256 thr. Per block: 64 t-rows of one (b,h).
// Q,K rotated+stored row-contiguous; V transposed through LDS so V^T rows
// are written 128B-coalesced (old version did 2B scatter at 4KB stride).
__global__ __launch_bounds__(256)
void rope_apply(const ushort* __restrict__ qkv, const float2* __restrict__ tab,
                ushort* __restrict__ Q, ushort* __restrict__ Kd,
                ushort* __restrict__ VT) {
  __shared__ ushort vt[64][66];
  int t0 = blockIdx.x * 64;
  int bh = blockIdx.y;
  int b = bh >> 4, h = bh & 15;
  int f = threadIdx.x & 31, tg = threadIdx.x >> 5;  // tg 0..7
#pragma unroll
  for (int i = 0; i < 8; i++) {
    int tt = tg * 8 + i;
    int t = t0 + tt;
    const ushort* qr = qkv + (size_t)(b * TSEQ + t) * 3072 + h * 64 + f;
    float2 cs = tab[t * 32 + f];
    float c = cs.x, s = cs.y;
    float q1 = bf2f(qr[0]),    q2 = bf2f(qr[32]);
    float k1 = bf2f(qr[1024]), k2 = bf2f(qr[1056]);
    ushort* Qp = Q + ((size_t)bh * TSEQ + t) * HDIM;
    ushort* Kp = Kd + ((size_t)bh * TSEQ + t) * HDIM;
    Qp[f]      = f2bf(q1 * c - q2 * s);
    Qp[f + 32] = f2bf(q1 * s + q2 * c);
    Kp[f]      = f2bf(k1 * c - k2 * s);
    Kp[f + 32] = f2bf(k1 * s + k2 * c);
    vt[f][tt]      = qr[2048];   // V needs no rope: raw bf16 copy
    vt[f + 32][tt] = qr[2080];
  }
  __syncthreads();
  int t = threadIdx.x & 63, fg = threadIdx.x >> 6;  // fg 0..3
  ushort* Vp = VT + (size_t)bh * HDIM * TSEQ + t0 + t;
#pragma unroll
  for (int j = 0; j < 16; j++) {
    int ff = fg * 16 + j;
    Vp[(size_t)ff * TSEQ] = vt[ff][t];
  }
}

// ---------------- attention (flash, causal, fully swapped) -----------------
// grid (32 bh, 128 q-tiles) longest-first; 64 thr = 1 wave; 16 q-rows/wave.
// QK^T swapped (mfma(K,Q)) -> lane holds 16 scores of q-row lr (k-major):
// in-register softmax, 2 shfl_xor per reduce, exp2 domain.
// PV swapped too (mfma(V^T,P)) -> O^T accumulates with q=lane-local: rescale
// and 1/l are scalar per lane, no broadcast shuffles. P routed through a
// 16x64 XOR-swizzled LDS tile to build the B-fragment (contiguous-k) layout.
__global__ __launch_bounds__(64, 5)
void attn_kernel(const ushort* __restrict__ Q, const ushort* __restrict__ Kd,
                 const ushort* __restrict__ VT, ushort* __restrict__ O) {
  int bh = blockIdx.x;
  int mt = 127 - (int)blockIdx.y;   // longest-first
  int qw = mt * 16;
  int nt = (mt >> 2) + 1;           // 64-key tiles
  int lane = threadIdx.x & 63;
  int lr = lane & 15, lg = lane >> 4;
  int q_abs = qw + lr;

  const ushort* Qb = Q + (size_t)bh * TSEQ * HDIM;
  const ushort* Kb = Kd + (size_t)bh * TSEQ * HDIM;
  const ushort* Vb = VT + (size_t)bh * HDIM * TSEQ;

  __shared__ ushort pt[16 * 64];

  // Q pre-scaled by (1/sqrt(hd)) * log2(e) -> softmax in exp2 domain
  const float QS = 0.125f * 1.44269504088896340736f;
  bf16x8 aq0 = *(const bf16x8*)&Qb[(size_t)q_abs * HDIM + lg * 8];
  bf16x8 aq1 = *(const bf16x8*)&Qb[(size_t)q_abs * HDIM + 32 + lg * 8];
#pragma unroll
  for (int j = 0; j < 8; j++) {
    aq0[j] = (bf16_t)((float)aq0[j] * QS);
    aq1[j] = (bf16_t)((float)aq1[j] * QS);
  }

  float m_run = -1e30f, l_run = 0.0f;   // per-lane: stats of q-row lr
  f32x4 o[4] = {};                      // o[d][r] = O[q=lr][d*16+lg*4+r]

  for (int it = 0; it < nt; ++it) {
    int kt = it * 64;
    bool diag = (it == nt - 1);

    // QK^T (swapped): sa[cb][r] = S[k=kt+cb*16+lg*4+r][q=lr]
    f32x4 sa[4];
#pragma unroll
    for (int cb = 0; cb < 4; cb++) {
      const ushort* kp = &Kb[(size_t)(kt + cb * 16 + lr) * HDIM + lg * 8];
      bf16x8 k0 = *(const bf16x8*)kp;
      bf16x8 k1 = *(const bf16x8*)(kp + 32);
      f32x4 z = {};
      z = mfma16(k0, aq0, z);
      sa[cb] = mfma16(k1, aq1, z);
    }

    // V A-fragments for PV (issued early; consumed after softmax)
    bf16x8 va0[4], va1[4];
#pragma unroll
    for (int d = 0; d < 4; d++) {
      const ushort* vp = &Vb[(size_t)(d * 16 + lr) * TSEQ + kt + lg * 8];
      va0[d] = *(const bf16x8*)vp;
      va1[d] = *(const bf16x8*)(vp + 32);
    }

    if (diag) {
#pragma unroll
      for (int cb = 0; cb < 4; cb++)
#pragma unroll
        for (int r = 0; r < 4; r++)
          if (kt + cb * 16 + lg * 4 + r > q_abs) sa[cb][r] = -1e30f;
    }

    // row max (tree + 2 shfl)
    f32x4 m4;
#pragma unroll
    for (int r = 0; r < 4; r++)
      m4[r] = fmaxf(fmaxf(sa[0][r], sa[1][r]), fmaxf(sa[2][r], sa[3][r]));
    float mx = fmaxf(fmaxf(m4[0], m4[1]), fmaxf(m4[2], m4[3]));
    mx = fmaxf(mx, __shfl_xor(mx, 16, 64));
    mx = fmaxf(mx, __shfl_xor(mx, 32, 64));
    float mn = fmaxf(m_run, mx);
    float rescale = __builtin_amdgcn_exp2f(m_run - mn);
    m_run = mn;

    // exp2 + sum + pack
    float ps = 0.0f;
    uint2 pk[4];
#pragma unroll
    for (int cb = 0; cb < 4; cb++) {
      float p0 = __builtin_amdgcn_exp2f(sa[cb][0] - mn);
      float p1 = __builtin_amdgcn_exp2f(sa[cb][1] - mn);
      float p2 = __builtin_amdgcn_exp2f(sa[cb][2] - mn);
      float p3 = __builtin_amdgcn_exp2f(sa[cb][3] - mn);
      ps += (p0 + p1) + (p2 + p3);
      pk[cb].x = cvt_pk_bf16(p0, p1);
      pk[cb].y = cvt_pk_bf16(p2, p3);
    }
    ps += __shfl_xor(ps, 16, 64);
    ps += __shfl_xor(ps, 32, 64);
    l_run = l_run * rescale + ps;

    // store P (swizzled, wave-local)
#pragma unroll
    for (int cb = 0; cb < 4; cb++)
      *(uint2*)&pt[lr * 64 + (((cb * 4 + lg) ^ lr) << 2)] = pk[cb];

    // rescale o (scalar per lane — q is lane-local now)
#pragma unroll
    for (int d = 0; d < 4; d++)
#pragma unroll
      for (int r = 0; r < 4; r++) o[d][r] *= rescale;

    // read P B-fragments: lane needs P[q=lr][k = c*32 + lg*8 .. +8]
    union U8 { uint2 h[2]; bf16x8 v; };
    U8 t0, t1;
    t0.h[0] = *(const uint2*)&pt[lr * 64 + (((lg * 2    ) ^ lr) << 2)];
    t0.h[1] = *(const uint2*)&pt[lr * 64 + (((lg * 2 + 1) ^ lr) << 2)];
    t1.h[0] = *(const uint2*)&pt[lr * 64 + (((8 + lg * 2    ) ^ lr) << 2)];
    t1.h[1] = *(const uint2*)&pt[lr * 64 + (((8 + lg * 2 + 1) ^ lr) << 2)];

    // PV (swapped): o[d] += V^T_frag x P_frag  -> O^T, q = lr
#pragma unroll
    for (int d = 0; d < 4; d++) {
      o[d] = mfma16(va0[d], t0.v, o[d]);
      o[d] = mfma16(va1[d], t1.v, o[d]);
    }
  }

  int b = bh >> 4, h = bh & 15;
  float linv = 1.0f / l_run;
  size_t obase = (size_t)(b * TSEQ + qw + lr) * DMODEL + h * 64;
#pragma unroll
  for (int d = 0; d < 4; d++) {
    uint2 st;
    st.x = cvt_pk_bf16(o[d][0] * linv, o[d][1] * linv);
    st.y = cvt_pk_bf16(o[d][2] * linv, o[d][3] * linv);
    *(uint2*)&O[obase + d * 16 + lg * 4] = st;
  }
}

// ---------------- GEMM: C(M,N) = A(M,K) @ Bt(N,K)^T, bf16 in, f32 acc ------
// 128x128 tile, BK=32, 4 waves in 2x2, 16x16x32 MFMA (m97 structure).
template <int EPI>
__global__ __launch_bounds__(256)
void gemm_kernel(const ushort* __restrict__ A, const ushort* __restrict__ Bt,
                 void* __restrict__ Cout, const float* __restrict__ bias,
                 const float* __restrict__ resid, int M, int N, int K) {
  __shared__ ushort lA[128 * 32];
  __shared__ ushort lB[128 * 32];
  int tid = threadIdx.x;
  int lane = tid & 63, w = tid >> 6;
  int wm = w >> 1, wn = w & 1;
  int bm = blockIdx.x, bn = blockIdx.y;
  f32x4 acc[4][4] = {};

  const ushort* Ab = A + (size_t)bm * 128 * K;
  const ushort* Bb = Bt + (size_t)bn * 128 * K;
  int srow = tid >> 2, scol = (tid & 3) * 8;
  int lrow = lane & 15, lk = (lane >> 4) * 8;

  for (int k0 = 0; k0 < K; k0 += 32) {
    __syncthreads();
    gload_lds16(Ab + (size_t)srow * K + k0 + scol, &lA[tid * 8]);
    gload_lds16(Ab + (size_t)(srow + 64) * K + k0 + scol, &lA[(tid + 256) * 8]);
    gload_lds16(Bb + (size_t)srow * K + k0 + scol, &lB[tid * 8]);
    gload_lds16(Bb + (size_t)(srow + 64) * K + k0 + scol, &lB[(tid + 256) * 8]);
    __syncthreads();
    bf16x8 af[4], bfr[4];
#pragma unroll
    for (int m = 0; m < 4; m++)
      af[m] = *(const bf16x8*)&lA[(wm * 64 + m * 16 + lrow) * 32 + lk];
#pragma unroll
    for (int n = 0; n < 4; n++)
      bfr[n] = *(const bf16x8*)&lB[(wn * 64 + n * 16 + lrow) * 32 + lk];
#pragma unroll
    for (int m = 0; m < 4; m++)
#pragma unroll
      for (int n = 0; n < 4; n++)
        acc[m][n] = mfma16(af[m], bfr[n], acc[m][n]);
  }

#pragma unroll
  for (int m = 0; m < 4; m++) {
    int rbase = bm * 128 + wm * 64 + m * 16 + (lane >> 4) * 4;
#pragma unroll
    for (int n = 0; n < 4; n++) {
      int c = bn * 128 + wn * 64 + n * 16 + (lane & 15);
#pragma unroll
      for (int r = 0; r < 4; r++) {
        float v = acc[m][n][r];
        size_t idx = (size_t)(rbase + r) * N + c;
        if constexpr (EPI == 0) {
          ((ushort*)Cout)[idx] = f2bf(v);
        } else if constexpr (EPI == 1) {
          ((float*)Cout)[idx] = v + resid[idx];
        } else if constexpr (EPI == 2) {
          ((ushort*)Cout)[idx] = f2bf(gelu_f(v + bias[c]));
        } else {
          ((float*)Cout)[idx] = v + bias[c] + resid[idx];
        }
      }
    }
  }
}

// ---------------------------------------------------------------------------
extern "C" void kernel_launch(void* const* d_in, const int* in_sizes, int n_in,
                              void* d_out, int out_size, void* d_ws,
                              size_t ws_size, hipStream_t stream) {
  const float* x      = (const float*)d_in[0];
  const int* positions = (const int*)d_in[1];
  const float* ln1_s  = (const float*)d_in[3];
  const float* ln1_b  = (const float*)d_in[4];
  const float* w_qkv  = (const float*)d_in[5];
  const float* w_o    = (const float*)d_in[6];
  const float* ln2_s  = (const float*)d_in[7];
  const float* ln2_b  = (const float*)d_in[8];
  const float* w1     = (const float*)d_in[9];
  const float* b1     = (const float*)d_in[10];
  const float* w2     = (const float*)d_in[11];
  const float* b2     = (const float*)d_in[12];
  float* out = (float*)d_out;

  char* ws = (char*)d_ws;
  size_t off = 0;
  auto nxt = [&](size_t bytes) {
    char* p = ws + off;
    off += (bytes + 255) & ~(size_t)255;
    return p;
  };
  ushort* wqkvT = (ushort*)nxt(3072ULL * 1024 * 2);
  ushort* woT   = (ushort*)nxt(1024ULL * 1024 * 2);
  ushort* w1T   = (ushort*)nxt(4096ULL * 1024 * 2);
  ushort* w2T   = (ushort*)nxt(1024ULL * 4096 * 2);
  ushort* h1    = (ushort*)nxt((size_t)M_ROWS * DMODEL * 2);
  ushort* qkv   = (ushort*)nxt((size_t)M_ROWS * 3072 * 2);
  ushort* Qb    = (ushort*)nxt(2ULL * NHEAD * TSEQ * HDIM * 2);
  ushort* Kb    = (ushort*)nxt(2ULL * NHEAD * TSEQ * HDIM * 2);
  ushort* VTb   = (ushort*)nxt(2ULL * NHEAD * TSEQ * HDIM * 2);
  ushort* attn  = (ushort*)nxt((size_t)M_ROWS * DMODEL * 2);
  float*  x2    = (float*)nxt((size_t)M_ROWS * DMODEL * 4);
  ushort* h2    = (ushort*)nxt((size_t)M_ROWS * DMODEL * 2);
  ushort* mid   = (ushort*)nxt((size_t)M_ROWS * 4096 * 2);
  float2* tab   = (float2*)nxt((size_t)TSEQ * 32 * 8);

  transpose_bf16<<<dim3(3072 / 32, 1024 / 32), 256, 0, stream>>>(w_qkv, wqkvT, 1024, 3072);
  transpose_bf16<<<dim3(1024 / 32, 1024 / 32), 256, 0, stream>>>(w_o, woT, 1024, 1024);
  transpose_bf16<<<dim3(4096 / 32, 1024 / 32), 256, 0, stream>>>(w1, w1T, 1024, 4096);
  transpose_bf16<<<dim3(1024 / 32, 4096 / 32), 256, 0, stream>>>(w2, w2T, 4096, 1024);
  rope_table<<<(TSEQ * 32) / 256, 256, 0, stream>>>(positions, tab);
  ln_kernel<<<M_ROWS, 256, 0, stream>>>(x, ln1_s, ln1_b, h1);
  gemm_kernel<0><<<dim3(32, 24), 256, 0, stream>>>(h1, wqkvT, qkv, nullptr, nullptr, 4096, 3072, 1024);
  rope_apply<<<dim3(TSEQ / 64, 2 * NHEAD), 256, 0, stream>>>(qkv, tab, Qb, Kb, VTb);
  attn_kernel<<<dim3(32, 128), 64, 0, stream>>>(Qb, Kb, VTb, attn);
  gemm_kernel<1><<<dim3(32, 8), 256, 0, stream>>>(attn, woT, x2, nullptr, x, 4096, 1024, 1024);
  ln_kernel<<<M_ROWS, 256, 0, stream>>>(x2, ln2_s, ln2_b, h2);
  gemm_kernel<2><<<dim3(32, 32), 256, 0, stream>>>(h2, w1T, mid, b1, nullptr, 4096, 4096, 1024);
  gemm_kernel<3><<<dim3(32, 8), 256, 0, stream>>>(mid, w2T, out, b2, x2, 4096, 1024, 4096);
}

// Round 5
// 294.092 us; speedup vs baseline: 1.7056x; 1.2805x over previous
//
#include <hip/hip_runtime.h>

// Decoder block: B=2 T=2048 D=1024 H=16 hd=64 HIDDEN=4096. All f32 in/out,
// bf16 MFMA internally (threshold is bf16-floor).

typedef __bf16 bf16_t;
typedef bf16_t bf16x8 __attribute__((ext_vector_type(8)));
typedef float f32x4 __attribute__((ext_vector_type(4)));

#define M_ROWS 4096   // B*T
#define DMODEL 1024
#define TSEQ   2048
#define NHEAD  16
#define HDIM   64

__device__ __forceinline__ ushort f2bf(float f) {
  union { float f; unsigned u; } v; v.f = f;
  unsigned r = (v.u + 0x7fffu + ((v.u >> 16) & 1u)) >> 16;
  return (ushort)r;
}
__device__ __forceinline__ float bf2f(ushort u) {
  union { unsigned u; float f; } v; v.u = ((unsigned)u) << 16;
  return v.f;
}
__device__ __forceinline__ unsigned cvt_pk_bf16(float a, float b) {
  unsigned r;
  asm("v_cvt_pk_bf16_f32 %0, %1, %2" : "=v"(r) : "v"(a), "v"(b));
  return r;
}
__device__ __forceinline__ void gload_lds16(const void* g, void* l) {
  __builtin_amdgcn_global_load_lds(
      (const __attribute__((address_space(1))) unsigned*)g,
      (__attribute__((address_space(3))) unsigned*)l, 16, 0, 0);
}
__device__ __forceinline__ f32x4 mfma16(bf16x8 a, bf16x8 b, f32x4 c) {
  return __builtin_amdgcn_mfma_f32_16x16x32_bf16(a, b, c, 0, 0, 0);
}
__device__ __forceinline__ float gelu_f(float x) {
  float y = 0.7978845608028654f * (x + 0.044715f * x * x * x);
  float e = __expf(2.0f * y);
  float t = 1.0f - 2.0f / (e + 1.0f);   // tanh(y), overflow-safe
  return 0.5f * x * (1.0f + t);
}

// ---------------- weight transpose + f32->bf16 -----------------------------
__global__ __launch_bounds__(256)
void transpose_bf16(const float* __restrict__ src, ushort* __restrict__ dst,
                    int K, int N) {
  __shared__ float t[32][33];
  int n0 = blockIdx.x * 32, k0 = blockIdx.y * 32;
  int tx = threadIdx.x & 31, ty = threadIdx.x >> 5;
#pragma unroll
  for (int i = 0; i < 4; i++) {
    int k = ty + i * 8;
    t[k][tx] = src[(size_t)(k0 + k) * N + n0 + tx];
  }
  __syncthreads();
#pragma unroll
  for (int i = 0; i < 4; i++) {
    int nn = ty + i * 8;
    dst[(size_t)(n0 + nn) * K + k0 + tx] = f2bf(t[tx][nn]);
  }
}

// ---------------- layernorm (f32 in, bf16 out) -----------------------------
__global__ __launch_bounds__(256)
void ln_kernel(const float* __restrict__ x, const float* __restrict__ sc,
               const float* __restrict__ bi, ushort* __restrict__ out) {
  int row = blockIdx.x;
  int tid = threadIdx.x;
  const float4 v = *(const float4*)&x[(size_t)row * DMODEL + tid * 4];
  float s = v.x + v.y + v.z + v.w;
  float s2 = v.x * v.x + v.y * v.y + v.z * v.z + v.w * v.w;
#pragma unroll
  for (int off = 32; off > 0; off >>= 1) {
    s += __shfl_down(s, off);
    s2 += __shfl_down(s2, off);
  }
  __shared__ float red[8];
  int lane = tid & 63, w = tid >> 6;
  if (lane == 0) { red[w * 2] = s; red[w * 2 + 1] = s2; }
  __syncthreads();
  float S = red[0] + red[2] + red[4] + red[6];
  float S2 = red[1] + red[3] + red[5] + red[7];
  float mu = S * (1.0f / DMODEL);
  float var = S2 * (1.0f / DMODEL) - mu * mu;
  float rs = rsqrtf(var + 1e-6f);
  float4 scv = *(const float4*)&sc[tid * 4];
  float4 biv = *(const float4*)&bi[tid * 4];
  ushort4 o;
  o.x = f2bf((v.x - mu) * rs * scv.x + biv.x);
  o.y = f2bf((v.y - mu) * rs * scv.y + biv.y);
  o.z = f2bf((v.z - mu) * rs * scv.z + biv.z);
  o.w = f2bf((v.w - mu) * rs * scv.w + biv.w);
  *(ushort4*)&out[(size_t)row * DMODEL + tid * 4] = o;
}

// ---------------- rope table -----------------------------------------------
__global__ __launch_bounds__(256)
void rope_table(const int* __restrict__ positions, float2* __restrict__ tab) {
  int i = blockIdx.x * 256 + threadIdx.x;  // T*32
  int t = i >> 5, f = i & 31;
  float inv = __expf(-(float)f * (1.0f / 32.0f) * 9.210340371976184f);
  float a = (float)positions[t] * inv;
  tab[i] = make_float2(cosf(a), sinf(a));
}

// ---------------- rope apply + QKV reshape ---------------------------------
// grid (T/64, B*H), 256 thr. Per block: 64 t-rows of one (b,h).
__global__ __launch_bounds__(256)
void rope_apply(const ushort* __restrict__ qkv, const float2* __restrict__ tab,
                ushort* __restrict__ Q, ushort* __restrict__ Kd,
                ushort* __restrict__ VT) {
  __shared__ ushort vt[64][66];
  int t0 = blockIdx.x * 64;
  int bh = blockIdx.y;
  int b = bh >> 4, h = bh & 15;
  int f = threadIdx.x & 31, tg = threadIdx.x >> 5;  // tg 0..7
#pragma unroll
  for (int i = 0; i < 8; i++) {
    int tt = tg * 8 + i;
    int t = t0 + tt;
    const ushort* qr = qkv + (size_t)(b * TSEQ + t) * 3072 + h * 64 + f;
    float2 cs = tab[t * 32 + f];
    float c = cs.x, s = cs.y;
    float q1 = bf2f(qr[0]),    q2 = bf2f(qr[32]);
    float k1 = bf2f(qr[1024]), k2 = bf2f(qr[1056]);
    ushort* Qp = Q + ((size_t)bh * TSEQ + t) * HDIM;
    ushort* Kp = Kd + ((size_t)bh * TSEQ + t) * HDIM;
    Qp[f]      = f2bf(q1 * c - q2 * s);
    Qp[f + 32] = f2bf(q1 * s + q2 * c);
    Kp[f]      = f2bf(k1 * c - k2 * s);
    Kp[f + 32] = f2bf(k1 * s + k2 * c);
    vt[f][tt]      = qr[2048];   // V needs no rope: raw bf16 copy
    vt[f + 32][tt] = qr[2080];
  }
  __syncthreads();
  int t = threadIdx.x & 63, fg = threadIdx.x >> 6;  // fg 0..3
  ushort* Vp = VT + (size_t)bh * HDIM * TSEQ + t0 + t;
#pragma unroll
  for (int j = 0; j < 16; j++) {
    int ff = fg * 16 + j;
    Vp[(size_t)ff * TSEQ] = vt[ff][t];
  }
}

// ---------------- attention (flash, causal, 4-wave LDS-staged) -------------
// grid (32 bh, 32 qb) longest-first; 256 thr = 4 waves; Q-tile 64 rows
// (wave w owns rows qb*64+w*16..+16); KVBLK=64.
// K (row-major [key][64]) and V^T ([dim][key]) staged in LDS via
// global_load_lds width-16, double-buffered, XOR-swizzled (chunk ^= row&7;
// linear LDS dest + inverse-swizzled global source + swizzled read).
// Stage of tile i+1 issued before compute of tile i; one barrier per tile.
// Per-wave math: swapped QK^T (lane holds q-row lr, k-major), in-register
// softmax (exp2 domain, 2 shfl per reduce), P via wave-local swizzled LDS
// tile, swapped PV (O^T, q lane-local).
__global__ __launch_bounds__(256, 4)
void attn_kernel(const ushort* __restrict__ Q, const ushort* __restrict__ Kd,
                 const ushort* __restrict__ VT, ushort* __restrict__ O) {
  int bh = blockIdx.x;
  int qb = 31 - (int)blockIdx.y;    // longest-first
  int nt = qb + 1;                  // 64-key tiles
  int tid = threadIdx.x;
  int lane = tid & 63, w = tid >> 6;
  int qw = qb * 64 + w * 16;
  int lr = lane & 15, lg = lane >> 4;
  int q_abs = qw + lr;

  const ushort* Qb = Q + (size_t)bh * TSEQ * HDIM;
  const ushort* Kb = Kd + (size_t)bh * TSEQ * HDIM;
  const ushort* Vb = VT + (size_t)bh * HDIM * TSEQ;

  __shared__ ushort lK[2][64 * 64];
  __shared__ ushort lV[2][64 * 64];
  __shared__ ushort pt[4][16 * 64];
  ushort* myp = pt[w];

  // staging geometry: 2 calls per tile per array; call c stages rows
  // c*32 + (tid>>3), chunk tid&7; source chunk = (tid&7) ^ (row&7).
  int srow0 = tid >> 3, sch = tid & 7;

  auto stage = [&](int buf, int kt) {
#pragma unroll
    for (int c = 0; c < 2; c++) {
      int r = c * 32 + srow0;
      int gch = sch ^ (r & 7);
      gload_lds16(Kb + (size_t)(kt + r) * HDIM + gch * 8,
                  &lK[buf][c * 2048 + tid * 8]);
      gload_lds16(Vb + (size_t)r * TSEQ + kt + gch * 8,
                  &lV[buf][c * 2048 + tid * 8]);
    }
  };

  // Q pre-scaled by (1/sqrt(hd)) * log2(e) -> softmax in exp2 domain
  const float QS = 0.125f * 1.44269504088896340736f;
  bf16x8 aq0 = *(const bf16x8*)&Qb[(size_t)q_abs * HDIM + lg * 8];
  bf16x8 aq1 = *(const bf16x8*)&Qb[(size_t)q_abs * HDIM + 32 + lg * 8];
#pragma unroll
  for (int j = 0; j < 8; j++) {
    aq0[j] = (bf16_t)((float)aq0[j] * QS);
    aq1[j] = (bf16_t)((float)aq1[j] * QS);
  }

  float m_run = -1e30f, l_run = 0.0f;   // per-lane: stats of q-row lr
  f32x4 o[4] = {};                      // o[d][r] = O[q=lr][d*16+lg*4+r]

  stage(0, 0);
  __syncthreads();

  for (int it = 0; it < nt; ++it) {
    int kt = it * 64;
    int buf = it & 1;
    bool diag = (it == nt - 1);

    if (it + 1 < nt) stage(buf ^ 1, kt + 64);

    // QK^T (swapped): sa[cb][r] = S[k=kt+cb*16+lg*4+r][q=lr]
    f32x4 sa[4];
#pragma unroll
    for (int cb = 0; cb < 4; cb++) {
      int row = cb * 16 + lr;
      const ushort* kp = &lK[buf][row * 64];
      bf16x8 k0 = *(const bf16x8*)(kp + (((lg    ) ^ (row & 7)) << 3));
      bf16x8 k1 = *(const bf16x8*)(kp + (((lg + 4) ^ (row & 7)) << 3));
      f32x4 z = {};
      z = mfma16(k0, aq0, z);
      sa[cb] = mfma16(k1, aq1, z);
    }

    if (diag) {
#pragma unroll
      for (int cb = 0; cb < 4; cb++)
#pragma unroll
        for (int r = 0; r < 4; r++)
          if (kt + cb * 16 + lg * 4 + r > q_abs) sa[cb][r] = -1e30f;
    }

    // row max (tree + 2 shfl)
    f32x4 m4;
#pragma unroll
    for (int r = 0; r < 4; r++)
      m4[r] = fmaxf(fmaxf(sa[0][r], sa[1][r]), fmaxf(sa[2][r], sa[3][r]));
    float mx = fmaxf(fmaxf(m4[0], m4[1]), fmaxf(m4[2], m4[3]));
    mx = fmaxf(mx, __shfl_xor(mx, 16, 64));
    mx = fmaxf(mx, __shfl_xor(mx, 32, 64));
    float mn = fmaxf(m_run, mx);
    float rescale = __builtin_amdgcn_exp2f(m_run - mn);
    m_run = mn;

    // exp2 + sum + pack
    float ps = 0.0f;
    uint2 pk[4];
#pragma unroll
    for (int cb = 0; cb < 4; cb++) {
      float p0 = __builtin_amdgcn_exp2f(sa[cb][0] - mn);
      float p1 = __builtin_amdgcn_exp2f(sa[cb][1] - mn);
      float p2 = __builtin_amdgcn_exp2f(sa[cb][2] - mn);
      float p3 = __builtin_amdgcn_exp2f(sa[cb][3] - mn);
      ps += (p0 + p1) + (p2 + p3);
      pk[cb].x = cvt_pk_bf16(p0, p1);
      pk[cb].y = cvt_pk_bf16(p2, p3);
    }
    ps += __shfl_xor(ps, 16, 64);
    ps += __shfl_xor(ps, 32, 64);
    l_run = l_run * rescale + ps;

    // store P (swizzled, wave-local)
#pragma unroll
    for (int cb = 0; cb < 4; cb++)
      *(uint2*)&myp[lr * 64 + (((cb * 4 + lg) ^ lr) << 2)] = pk[cb];

    // rescale o (scalar per lane — q is lane-local)
#pragma unroll
    for (int d = 0; d < 4; d++)
#pragma unroll
      for (int r = 0; r < 4; r++) o[d][r] *= rescale;

    // read P B-fragments: lane needs P[q=lr][k = c*32 + lg*8 .. +8]
    union U8 { uint2 h[2]; bf16x8 v; };
    U8 t0, t1;
    t0.h[0] = *(const uint2*)&myp[lr * 64 + (((lg * 2    ) ^ lr) << 2)];
    t0.h[1] = *(const uint2*)&myp[lr * 64 + (((lg * 2 + 1) ^ lr) << 2)];
    t1.h[0] = *(const uint2*)&myp[lr * 64 + (((8 + lg * 2    ) ^ lr) << 2)];
    t1.h[1] = *(const uint2*)&myp[lr * 64 + (((8 + lg * 2 + 1) ^ lr) << 2)];

    // PV (swapped): o[d] += V^T_frag x P_frag  -> O^T, q = lr
#pragma unroll
    for (int d = 0; d < 4; d++) {
      int row = d * 16 + lr;
      const ushort* vp = &lV[buf][row * 64];
      bf16x8 va0 = *(const bf16x8*)(vp + (((lg    ) ^ (row & 7)) << 3));
      bf16x8 va1 = *(const bf16x8*)(vp + (((lg + 4) ^ (row & 7)) << 3));
      o[d] = mfma16(va0, t0.v, o[d]);
      o[d] = mfma16(va1, t1.v, o[d]);
    }

    __syncthreads();
  }

  int b = bh >> 4, h = bh & 15;
  float linv = 1.0f / l_run;
  size_t obase = (size_t)(b * TSEQ + qw + lr) * DMODEL + h * 64;
#pragma unroll
  for (int d = 0; d < 4; d++) {
    uint2 st;
    st.x = cvt_pk_bf16(o[d][0] * linv, o[d][1] * linv);
    st.y = cvt_pk_bf16(o[d][2] * linv, o[d][3] * linv);
    *(uint2*)&O[obase + d * 16 + lg * 4] = st;
  }
}

// ---------------- GEMM: C(M,N) = A(M,K) @ Bt(N,K)^T, bf16 in, f32 acc ------
// 128x128 tile, BK=32, 4 waves in 2x2, 16x16x32 MFMA (m97 structure).
template <int EPI>
__global__ __launch_bounds__(256)
void gemm_kernel(const ushort* __restrict__ A, const ushort* __restrict__ Bt,
                 void* __restrict__ Cout, const float* __restrict__ bias,
                 const float* __restrict__ resid, int M, int N, int K) {
  __shared__ ushort lA[128 * 32];
  __shared__ ushort lB[128 * 32];
  int tid = threadIdx.x;
  int lane = tid & 63, w = tid >> 6;
  int wm = w >> 1, wn = w & 1;
  int bm = blockIdx.x, bn = blockIdx.y;
  f32x4 acc[4][4] = {};

  const ushort* Ab = A + (size_t)bm * 128 * K;
  const ushort* Bb = Bt + (size_t)bn * 128 * K;
  int srow = tid >> 2, scol = (tid & 3) * 8;
  int lrow = lane & 15, lk = (lane >> 4) * 8;

  for (int k0 = 0; k0 < K; k0 += 32) {
    __syncthreads();
    gload_lds16(Ab + (size_t)srow * K + k0 + scol, &lA[tid * 8]);
    gload_lds16(Ab + (size_t)(srow + 64) * K + k0 + scol, &lA[(tid + 256) * 8]);
    gload_lds16(Bb + (size_t)srow * K + k0 + scol, &lB[tid * 8]);
    gload_lds16(Bb + (size_t)(srow + 64) * K + k0 + scol, &lB[(tid + 256) * 8]);
    __syncthreads();
    bf16x8 af[4], bfr[4];
#pragma unroll
    for (int m = 0; m < 4; m++)
      af[m] = *(const bf16x8*)&lA[(wm * 64 + m * 16 + lrow) * 32 + lk];
#pragma unroll
    for (int n = 0; n < 4; n++)
      bfr[n] = *(const bf16x8*)&lB[(wn * 64 + n * 16 + lrow) * 32 + lk];
#pragma unroll
    for (int m = 0; m < 4; m++)
#pragma unroll
      for (int n = 0; n < 4; n++)
        acc[m][n] = mfma16(af[m], bfr[n], acc[m][n]);
  }

#pragma unroll
  for (int m = 0; m < 4; m++) {
    int rbase = bm * 128 + wm * 64 + m * 16 + (lane >> 4) * 4;
#pragma unroll
    for (int n = 0; n < 4; n++) {
      int c = bn * 128 + wn * 64 + n * 16 + (lane & 15);
#pragma unroll
      for (int r = 0; r < 4; r++) {
        float v = acc[m][n][r];
        size_t idx = (size_t)(rbase + r) * N + c;
        if constexpr (EPI == 0) {
          ((ushort*)Cout)[idx] = f2bf(v);
        } else if constexpr (EPI == 1) {
          ((float*)Cout)[idx] = v + resid[idx];
        } else if constexpr (EPI == 2) {
          ((ushort*)Cout)[idx] = f2bf(gelu_f(v + bias[c]));
        } else {
          ((float*)Cout)[idx] = v + bias[c] + resid[idx];
        }
      }
    }
  }
}

// ---------------------------------------------------------------------------
extern "C" void kernel_launch(void* const* d_in, const int* in_sizes, int n_in,
                              void* d_out, int out_size, void* d_ws,
                              size_t ws_size, hipStream_t stream) {
  const float* x      = (const float*)d_in[0];
  const int* positions = (const int*)d_in[1];
  const float* ln1_s  = (const float*)d_in[3];
  const float* ln1_b  = (const float*)d_in[4];
  const float* w_qkv  = (const float*)d_in[5];
  const float* w_o    = (const float*)d_in[6];
  const float* ln2_s  = (const float*)d_in[7];
  const float* ln2_b  = (const float*)d_in[8];
  const float* w1     = (const float*)d_in[9];
  const float* b1     = (const float*)d_in[10];
  const float* w2     = (const float*)d_in[11];
  const float* b2     = (const float*)d_in[12];
  float* out = (float*)d_out;

  char* ws = (char*)d_ws;
  size_t off = 0;
  auto nxt = [&](size_t bytes) {
    char* p = ws + off;
    off += (bytes + 255) & ~(size_t)255;
    return p;
  };
  ushort* wqkvT = (ushort*)nxt(3072ULL * 1024 * 2);
  ushort* woT   = (ushort*)nxt(1024ULL * 1024 * 2);
  ushort* w1T   = (ushort*)nxt(4096ULL * 1024 * 2);
  ushort* w2T   = (ushort*)nxt(1024ULL * 4096 * 2);
  ushort* h1    = (ushort*)nxt((size_t)M_ROWS * DMODEL * 2);
  ushort* qkv   = (ushort*)nxt((size_t)M_ROWS * 3072 * 2);
  ushort* Qb    = (ushort*)nxt(2ULL * NHEAD * TSEQ * HDIM * 2);
  ushort* Kb    = (ushort*)nxt(2ULL * NHEAD * TSEQ * HDIM * 2);
  ushort* VTb   = (ushort*)nxt(2ULL * NHEAD * TSEQ * HDIM * 2);
  ushort* attn  = (ushort*)nxt((size_t)M_ROWS * DMODEL * 2);
  float*  x2    = (float*)nxt((size_t)M_ROWS * DMODEL * 4);
  ushort* h2    = (ushort*)nxt((size_t)M_ROWS * DMODEL * 2);
  ushort* mid   = (ushort*)nxt((size_t)M_ROWS * 4096 * 2);
  float2* tab   = (float2*)nxt((size_t)TSEQ * 32 * 8);

  transpose_bf16<<<dim3(3072 / 32, 1024 / 32), 256, 0, stream>>>(w_qkv, wqkvT, 1024, 3072);
  transpose_bf16<<<dim3(1024 / 32, 1024 / 32), 256, 0, stream>>>(w_o, woT, 1024, 1024);
  transpose_bf16<<<dim3(4096 / 32, 1024 / 32), 256, 0, stream>>>(w1, w1T, 1024, 4096);
  transpose_bf16<<<dim3(1024 / 32, 4096 / 32), 256, 0, stream>>>(w2, w2T, 4096, 1024);
  rope_table<<<(TSEQ * 32) / 256, 256, 0, stream>>>(positions, tab);
  ln_kernel<<<M_ROWS, 256, 0, stream>>>(x, ln1_s, ln1_b, h1);
  gemm_kernel<0><<<dim3(32, 24), 256, 0, stream>>>(h1, wqkvT, qkv, nullptr, nullptr, 4096, 3072, 1024);
  rope_apply<<<dim3(TSEQ / 64, 2 * NHEAD), 256, 0, stream>>>(qkv, tab, Qb, Kb, VTb);
  attn_kernel<<<dim3(32, 32), 256, 0, stream>>>(Qb, Kb, VTb, attn);
  gemm_kernel<1><<<dim3(32, 8), 256, 0, stream>>>(attn, woT, x2, nullptr, x, 4096, 1024, 1024);
  ln_kernel<<<M_ROWS, 256, 0, stream>>>(x2, ln2_s, ln2_b, h2);
  gemm_kernel<2><<<dim3(32, 32), 256, 0, stream>>>(h2, w1T, mid, b1, nullptr, 4096, 4096, 1024);
  gemm_kernel<3><<<dim3(32, 8), 256, 0, stream>>>(mid, w2T, out, b2, x2, 4096, 1024, 4096);
}

// Round 6
// 252.643 us; speedup vs baseline: 1.9854x; 1.1641x over previous
//
#include <hip/hip_runtime.h>

// Decoder block: B=2 T=2048 D=1024 H=16 hd=64 HIDDEN=4096. All f32 in/out,
// bf16 MFMA internally (threshold is bf16-floor).

typedef __bf16 bf16_t;
typedef bf16_t bf16x8 __attribute__((ext_vector_type(8)));
typedef float f32x4 __attribute__((ext_vector_type(4)));

#define M_ROWS 4096   // B*T
#define DMODEL 1024
#define TSEQ   2048
#define NHEAD  16
#define HDIM   64

__device__ __forceinline__ ushort f2bf(float f) {
  union { float f; unsigned u; } v; v.f = f;
  unsigned r = (v.u + 0x7fffu + ((v.u >> 16) & 1u)) >> 16;
  return (ushort)r;
}
__device__ __forceinline__ float bf2f(ushort u) {
  union { unsigned u; float f; } v; v.u = ((unsigned)u) << 16;
  return v.f;
}
__device__ __forceinline__ unsigned cvt_pk_bf16(float a, float b) {
  unsigned r;
  asm("v_cvt_pk_bf16_f32 %0, %1, %2" : "=v"(r) : "v"(a), "v"(b));
  return r;
}
__device__ __forceinline__ void gload_lds16(const void* g, void* l) {
  __builtin_amdgcn_global_load_lds(
      (const __attribute__((address_space(1))) unsigned*)g,
      (__attribute__((address_space(3))) unsigned*)l, 16, 0, 0);
}
__device__ __forceinline__ f32x4 mfma16(bf16x8 a, bf16x8 b, f32x4 c) {
  return __builtin_amdgcn_mfma_f32_16x16x32_bf16(a, b, c, 0, 0, 0);
}
__device__ __forceinline__ float gelu_f(float x) {
  float y = 0.7978845608028654f * (x + 0.044715f * x * x * x);
  float e = __expf(2.0f * y);
  float t = 1.0f - 2.0f / (e + 1.0f);   // tanh(y), overflow-safe
  return 0.5f * x * (1.0f + t);
}

// ---------------- weight transpose + f32->bf16 -----------------------------
__global__ __launch_bounds__(256)
void transpose_bf16(const float* __restrict__ src, ushort* __restrict__ dst,
                    int K, int N) {
  __shared__ float t[32][33];
  int n0 = blockIdx.x * 32, k0 = blockIdx.y * 32;
  int tx = threadIdx.x & 31, ty = threadIdx.x >> 5;
#pragma unroll
  for (int i = 0; i < 4; i++) {
    int k = ty + i * 8;
    t[k][tx] = src[(size_t)(k0 + k) * N + n0 + tx];
  }
  __syncthreads();
#pragma unroll
  for (int i = 0; i < 4; i++) {
    int nn = ty + i * 8;
    dst[(size_t)(n0 + nn) * K + k0 + tx] = f2bf(t[tx][nn]);
  }
}

// ---------------- layernorm (f32 in, bf16 out) -----------------------------
__global__ __launch_bounds__(256)
void ln_kernel(const float* __restrict__ x, const float* __restrict__ sc,
               const float* __restrict__ bi, ushort* __restrict__ out) {
  int row = blockIdx.x;
  int tid = threadIdx.x;
  const float4 v = *(const float4*)&x[(size_t)row * DMODEL + tid * 4];
  float s = v.x + v.y + v.z + v.w;
  float s2 = v.x * v.x + v.y * v.y + v.z * v.z + v.w * v.w;
#pragma unroll
  for (int off = 32; off > 0; off >>= 1) {
    s += __shfl_down(s, off);
    s2 += __shfl_down(s2, off);
  }
  __shared__ float red[8];
  int lane = tid & 63, w = tid >> 6;
  if (lane == 0) { red[w * 2] = s; red[w * 2 + 1] = s2; }
  __syncthreads();
  float S = red[0] + red[2] + red[4] + red[6];
  float S2 = red[1] + red[3] + red[5] + red[7];
  float mu = S * (1.0f / DMODEL);
  float var = S2 * (1.0f / DMODEL) - mu * mu;
  float rs = rsqrtf(var + 1e-6f);
  float4 scv = *(const float4*)&sc[tid * 4];
  float4 biv = *(const float4*)&bi[tid * 4];
  ushort4 o;
  o.x = f2bf((v.x - mu) * rs * scv.x + biv.x);
  o.y = f2bf((v.y - mu) * rs * scv.y + biv.y);
  o.z = f2bf((v.z - mu) * rs * scv.z + biv.z);
  o.w = f2bf((v.w - mu) * rs * scv.w + biv.w);
  *(ushort4*)&out[(size_t)row * DMODEL + tid * 4] = o;
}

// ---------------- rope table -----------------------------------------------
__global__ __launch_bounds__(256)
void rope_table(const int* __restrict__ positions, float2* __restrict__ tab) {
  int i = blockIdx.x * 256 + threadIdx.x;  // T*32
  int t = i >> 5, f = i & 31;
  float inv = __expf(-(float)f * (1.0f / 32.0f) * 9.210340371976184f);
  float a = (float)positions[t] * inv;
  tab[i] = make_float2(cosf(a), sinf(a));
}

// ---------------- rope apply + QKV reshape ---------------------------------
// grid (T/64, B*H), 256 thr. Per block: 64 t-rows of one (b,h).
__global__ __launch_bounds__(256)
void rope_apply(const ushort* __restrict__ qkv, const float2* __restrict__ tab,
                ushort* __restrict__ Q, ushort* __restrict__ Kd,
                ushort* __restrict__ VT) {
  __shared__ ushort vt[64][66];
  int t0 = blockIdx.x * 64;
  int bh = blockIdx.y;
  int b = bh >> 4, h = bh & 15;
  int f = threadIdx.x & 31, tg = threadIdx.x >> 5;  // tg 0..7
#pragma unroll
  for (int i = 0; i < 8; i++) {
    int tt = tg * 8 + i;
    int t = t0 + tt;
    const ushort* qr = qkv + (size_t)(b * TSEQ + t) * 3072 + h * 64 + f;
    float2 cs = tab[t * 32 + f];
    float c = cs.x, s = cs.y;
    float q1 = bf2f(qr[0]),    q2 = bf2f(qr[32]);
    float k1 = bf2f(qr[1024]), k2 = bf2f(qr[1056]);
    ushort* Qp = Q + ((size_t)bh * TSEQ + t) * HDIM;
    ushort* Kp = Kd + ((size_t)bh * TSEQ + t) * HDIM;
    Qp[f]      = f2bf(q1 * c - q2 * s);
    Qp[f + 32] = f2bf(q1 * s + q2 * c);
    Kp[f]      = f2bf(k1 * c - k2 * s);
    Kp[f + 32] = f2bf(k1 * s + k2 * c);
    vt[f][tt]      = qr[2048];   // V needs no rope: raw bf16 copy
    vt[f + 32][tt] = qr[2080];
  }
  __syncthreads();
  int t = threadIdx.x & 63, fg = threadIdx.x >> 6;  // fg 0..3
  ushort* Vp = VT + (size_t)bh * HDIM * TSEQ + t0 + t;
#pragma unroll
  for (int j = 0; j < 16; j++) {
    int ff = fg * 16 + j;
    Vp[(size_t)ff * TSEQ] = vt[ff][t];
  }
}

// ---------------- attention (flash, causal, 4-wave LDS-staged) -------------
// (unchanged from round 5 — GEMM is the current bottleneck)
__global__ __launch_bounds__(256, 4)
void attn_kernel(const ushort* __restrict__ Q, const ushort* __restrict__ Kd,
                 const ushort* __restrict__ VT, ushort* __restrict__ O) {
  int bh = blockIdx.x;
  int qb = 31 - (int)blockIdx.y;    // longest-first
  int nt = qb + 1;                  // 64-key tiles
  int tid = threadIdx.x;
  int lane = tid & 63, w = tid >> 6;
  int qw = qb * 64 + w * 16;
  int lr = lane & 15, lg = lane >> 4;
  int q_abs = qw + lr;

  const ushort* Qb = Q + (size_t)bh * TSEQ * HDIM;
  const ushort* Kb = Kd + (size_t)bh * TSEQ * HDIM;
  const ushort* Vb = VT + (size_t)bh * HDIM * TSEQ;

  __shared__ ushort lK[2][64 * 64];
  __shared__ ushort lV[2][64 * 64];
  __shared__ ushort pt[4][16 * 64];
  ushort* myp = pt[w];

  int srow0 = tid >> 3, sch = tid & 7;

  auto stage = [&](int buf, int kt) {
#pragma unroll
    for (int c = 0; c < 2; c++) {
      int r = c * 32 + srow0;
      int gch = sch ^ (r & 7);
      gload_lds16(Kb + (size_t)(kt + r) * HDIM + gch * 8,
                  &lK[buf][c * 2048 + tid * 8]);
      gload_lds16(Vb + (size_t)r * TSEQ + kt + gch * 8,
                  &lV[buf][c * 2048 + tid * 8]);
    }
  };

  const float QS = 0.125f * 1.44269504088896340736f;
  bf16x8 aq0 = *(const bf16x8*)&Qb[(size_t)q_abs * HDIM + lg * 8];
  bf16x8 aq1 = *(const bf16x8*)&Qb[(size_t)q_abs * HDIM + 32 + lg * 8];
#pragma unroll
  for (int j = 0; j < 8; j++) {
    aq0[j] = (bf16_t)((float)aq0[j] * QS);
    aq1[j] = (bf16_t)((float)aq1[j] * QS);
  }

  float m_run = -1e30f, l_run = 0.0f;   // per-lane: stats of q-row lr
  f32x4 o[4] = {};                      // o[d][r] = O[q=lr][d*16+lg*4+r]

  stage(0, 0);
  __syncthreads();

  for (int it = 0; it < nt; ++it) {
    int kt = it * 64;
    int buf = it & 1;
    bool diag = (it == nt - 1);

    if (it + 1 < nt) stage(buf ^ 1, kt + 64);

    // QK^T (swapped): sa[cb][r] = S[k=kt+cb*16+lg*4+r][q=lr]
    f32x4 sa[4];
#pragma unroll
    for (int cb = 0; cb < 4; cb++) {
      int row = cb * 16 + lr;
      const ushort* kp = &lK[buf][row * 64];
      bf16x8 k0 = *(const bf16x8*)(kp + (((lg    ) ^ (row & 7)) << 3));
      bf16x8 k1 = *(const bf16x8*)(kp + (((lg + 4) ^ (row & 7)) << 3));
      f32x4 z = {};
      z = mfma16(k0, aq0, z);
      sa[cb] = mfma16(k1, aq1, z);
    }

    if (diag) {
#pragma unroll
      for (int cb = 0; cb < 4; cb++)
#pragma unroll
        for (int r = 0; r < 4; r++)
          if (kt + cb * 16 + lg * 4 + r > q_abs) sa[cb][r] = -1e30f;
    }

    // row max (tree + 2 shfl)
    f32x4 m4;
#pragma unroll
    for (int r = 0; r < 4; r++)
      m4[r] = fmaxf(fmaxf(sa[0][r], sa[1][r]), fmaxf(sa[2][r], sa[3][r]));
    float mx = fmaxf(fmaxf(m4[0], m4[1]), fmaxf(m4[2], m4[3]));
    mx = fmaxf(mx, __shfl_xor(mx, 16, 64));
    mx = fmaxf(mx, __shfl_xor(mx, 32, 64));
    float mn = fmaxf(m_run, mx);
    float rescale = __builtin_amdgcn_exp2f(m_run - mn);
    m_run = mn;

    // exp2 + sum + pack
    float ps = 0.0f;
    uint2 pk[4];
#pragma unroll
    for (int cb = 0; cb < 4; cb++) {
      float p0 = __builtin_amdgcn_exp2f(sa[cb][0] - mn);
      float p1 = __builtin_amdgcn_exp2f(sa[cb][1] - mn);
      float p2 = __builtin_amdgcn_exp2f(sa[cb][2] - mn);
      float p3 = __builtin_amdgcn_exp2f(sa[cb][3] - mn);
      ps += (p0 + p1) + (p2 + p3);
      pk[cb].x = cvt_pk_bf16(p0, p1);
      pk[cb].y = cvt_pk_bf16(p2, p3);
    }
    ps += __shfl_xor(ps, 16, 64);
    ps += __shfl_xor(ps, 32, 64);
    l_run = l_run * rescale + ps;

    // store P (swizzled, wave-local)
#pragma unroll
    for (int cb = 0; cb < 4; cb++)
      *(uint2*)&myp[lr * 64 + (((cb * 4 + lg) ^ lr) << 2)] = pk[cb];

    // rescale o (scalar per lane — q is lane-local)
#pragma unroll
    for (int d = 0; d < 4; d++)
#pragma unroll
      for (int r = 0; r < 4; r++) o[d][r] *= rescale;

    // read P B-fragments: lane needs P[q=lr][k = c*32 + lg*8 .. +8]
    union U8 { uint2 h[2]; bf16x8 v; };
    U8 t0, t1;
    t0.h[0] = *(const uint2*)&myp[lr * 64 + (((lg * 2    ) ^ lr) << 2)];
    t0.h[1] = *(const uint2*)&myp[lr * 64 + (((lg * 2 + 1) ^ lr) << 2)];
    t1.h[0] = *(const uint2*)&myp[lr * 64 + (((8 + lg * 2    ) ^ lr) << 2)];
    t1.h[1] = *(const uint2*)&myp[lr * 64 + (((8 + lg * 2 + 1) ^ lr) << 2)];

    // PV (swapped): o[d] += V^T_frag x P_frag  -> O^T, q = lr
#pragma unroll
    for (int d = 0; d < 4; d++) {
      int row = d * 16 + lr;
      const ushort* vp = &lV[buf][row * 64];
      bf16x8 va0 = *(const bf16x8*)(vp + (((lg    ) ^ (row & 7)) << 3));
      bf16x8 va1 = *(const bf16x8*)(vp + (((lg + 4) ^ (row & 7)) << 3));
      o[d] = mfma16(va0, t0.v, o[d]);
      o[d] = mfma16(va1, t1.v, o[d]);
    }

    __syncthreads();
  }

  int b = bh >> 4, h = bh & 15;
  float linv = 1.0f / l_run;
  size_t obase = (size_t)(b * TSEQ + qw + lr) * DMODEL + h * 64;
#pragma unroll
  for (int d = 0; d < 4; d++) {
    uint2 st;
    st.x = cvt_pk_bf16(o[d][0] * linv, o[d][1] * linv);
    st.y = cvt_pk_bf16(o[d][2] * linv, o[d][3] * linv);
    *(uint2*)&O[obase + d * 16 + lg * 4] = st;
  }
}

// ---------------- GEMM: C(M,N) = A(M,K) @ Bt(N,K)^T, bf16 in, f32 acc ------
// BM=128, BN template (128 or 64), BK=64 (32 MFMA per barrier), 4 waves 2x2.
// LDS chunk-XOR swizzle (chunk ^= row&7): linear LDS dest + inverse-swizzled
// global source + swizzled read -> conflict-free ds_read_b128.
// 1-D grid with bijective XCD swizzle (nwg % 8 == 0), bn-fastest decompose
// so each XCD chunk reuses one A-panel in its L2.
// EPI: 0 bf16 out; 1 +resid f32; 2 +bias,gelu bf16; 3 +bias+resid f32.
template <int EPI, int BN>
__global__ __launch_bounds__(256)
void gemm_kernel(const ushort* __restrict__ A, const ushort* __restrict__ Bt,
                 void* __restrict__ Cout, const float* __restrict__ bias,
                 const float* __restrict__ resid, int M, int N, int K,
                 int nbn) {
  constexpr int NF = BN / 32;           // n-frags per wave (4 or 2)
  __shared__ ushort lA[128 * 64];
  __shared__ ushort lB[BN * 64];
  int tid = threadIdx.x;
  int lane = tid & 63, w = tid >> 6;
  int wm = w >> 1, wn = w & 1;

  int nwg = gridDim.x;
  int cpx = nwg >> 3;
  int wg = ((int)blockIdx.x & 7) * cpx + ((int)blockIdx.x >> 3);
  int bm = wg / nbn, bn = wg % nbn;

  f32x4 acc[4][NF] = {};

  const ushort* Ab = A + (size_t)bm * 128 * K;
  const ushort* Bb = Bt + (size_t)bn * BN * K;
  int lrow = lane & 15, lg = lane >> 4;
  int srow = tid >> 3, sch = tid & 7;

  for (int k0 = 0; k0 < K; k0 += 64) {
    __syncthreads();
#pragma unroll
    for (int c = 0; c < 4; c++) {
      int r = c * 32 + srow;
      int gch = sch ^ (r & 7);
      gload_lds16(Ab + (size_t)r * K + k0 + gch * 8, &lA[c * 2048 + tid * 8]);
    }
#pragma unroll
    for (int c = 0; c < BN / 32; c++) {
      int r = c * 32 + srow;
      int gch = sch ^ (r & 7);
      gload_lds16(Bb + (size_t)r * K + k0 + gch * 8, &lB[c * 2048 + tid * 8]);
    }
    __syncthreads();

    bf16x8 af[4], bfr[NF];
    // k-step 0 (chunks lg ^ row)
#pragma unroll
    for (int m = 0; m < 4; m++) {
      int row = wm * 64 + m * 16 + lrow;
      af[m] = *(const bf16x8*)&lA[row * 64 + ((lg ^ (row & 7)) << 3)];
    }
#pragma unroll
    for (int n = 0; n < NF; n++) {
      int row = wn * (BN / 2) + n * 16 + lrow;
      bfr[n] = *(const bf16x8*)&lB[row * 64 + ((lg ^ (row & 7)) << 3)];
    }
#pragma unroll
    for (int m = 0; m < 4; m++)
#pragma unroll
      for (int n = 0; n < NF; n++)
        acc[m][n] = mfma16(af[m], bfr[n], acc[m][n]);
    // k-step 32 (chunks (4+lg) ^ row)
#pragma unroll
    for (int m = 0; m < 4; m++) {
      int row = wm * 64 + m * 16 + lrow;
      af[m] = *(const bf16x8*)&lA[row * 64 + (((4 + lg) ^ (row & 7)) << 3)];
    }
#pragma unroll
    for (int n = 0; n < NF; n++) {
      int row = wn * (BN / 2) + n * 16 + lrow;
      bfr[n] = *(const bf16x8*)&lB[row * 64 + (((4 + lg) ^ (row & 7)) << 3)];
    }
#pragma unroll
    for (int m = 0; m < 4; m++)
#pragma unroll
      for (int n = 0; n < NF; n++)
        acc[m][n] = mfma16(af[m], bfr[n], acc[m][n]);
  }

#pragma unroll
  for (int m = 0; m < 4; m++) {
    int rbase = bm * 128 + wm * 64 + m * 16 + (lane >> 4) * 4;
#pragma unroll
    for (int n = 0; n < NF; n++) {
      int c = bn * BN + wn * (BN / 2) + n * 16 + (lane & 15);
#pragma unroll
      for (int r = 0; r < 4; r++) {
        float v = acc[m][n][r];
        size_t idx = (size_t)(rbase + r) * N + c;
        if constexpr (EPI == 0) {
          ((ushort*)Cout)[idx] = f2bf(v);
        } else if constexpr (EPI == 1) {
          ((float*)Cout)[idx] = v + resid[idx];
        } else if constexpr (EPI == 2) {
          ((ushort*)Cout)[idx] = f2bf(gelu_f(v + bias[c]));
        } else {
          ((float*)Cout)[idx] = v + bias[c] + resid[idx];
        }
      }
    }
  }
}

// ---------------------------------------------------------------------------
extern "C" void kernel_launch(void* const* d_in, const int* in_sizes, int n_in,
                              void* d_out, int out_size, void* d_ws,
                              size_t ws_size, hipStream_t stream) {
  const float* x      = (const float*)d_in[0];
  const int* positions = (const int*)d_in[1];
  const float* ln1_s  = (const float*)d_in[3];
  const float* ln1_b  = (const float*)d_in[4];
  const float* w_qkv  = (const float*)d_in[5];
  const float* w_o    = (const float*)d_in[6];
  const float* ln2_s  = (const float*)d_in[7];
  const float* ln2_b  = (const float*)d_in[8];
  const float* w1     = (const float*)d_in[9];
  const float* b1     = (const float*)d_in[10];
  const float* w2     = (const float*)d_in[11];
  const float* b2     = (const float*)d_in[12];
  float* out = (float*)d_out;

  char* ws = (char*)d_ws;
  size_t off = 0;
  auto nxt = [&](size_t bytes) {
    char* p = ws + off;
    off += (bytes + 255) & ~(size_t)255;
    return p;
  };
  ushort* wqkvT = (ushort*)nxt(3072ULL * 1024 * 2);
  ushort* woT   = (ushort*)nxt(1024ULL * 1024 * 2);
  ushort* w1T   = (ushort*)nxt(4096ULL * 1024 * 2);
  ushort* w2T   = (ushort*)nxt(1024ULL * 4096 * 2);
  ushort* h1    = (ushort*)nxt((size_t)M_ROWS * DMODEL * 2);
  ushort* qkv   = (ushort*)nxt((size_t)M_ROWS * 3072 * 2);
  ushort* Qb    = (ushort*)nxt(2ULL * NHEAD * TSEQ * HDIM * 2);
  ushort* Kb    = (ushort*)nxt(2ULL * NHEAD * TSEQ * HDIM * 2);
  ushort* VTb   = (ushort*)nxt(2ULL * NHEAD * TSEQ * HDIM * 2);
  ushort* attn  = (ushort*)nxt((size_t)M_ROWS * DMODEL * 2);
  float*  x2    = (float*)nxt((size_t)M_ROWS * DMODEL * 4);
  ushort* h2    = (ushort*)nxt((size_t)M_ROWS * DMODEL * 2);
  ushort* mid   = (ushort*)nxt((size_t)M_ROWS * 4096 * 2);
  float2* tab   = (float2*)nxt((size_t)TSEQ * 32 * 8);

  transpose_bf16<<<dim3(3072 / 32, 1024 / 32), 256, 0, stream>>>(w_qkv, wqkvT, 1024, 3072);
  transpose_bf16<<<dim3(1024 / 32, 1024 / 32), 256, 0, stream>>>(w_o, woT, 1024, 1024);
  transpose_bf16<<<dim3(4096 / 32, 1024 / 32), 256, 0, stream>>>(w1, w1T, 1024, 4096);
  transpose_bf16<<<dim3(1024 / 32, 4096 / 32), 256, 0, stream>>>(w2, w2T, 4096, 1024);
  rope_table<<<(TSEQ * 32) / 256, 256, 0, stream>>>(positions, tab);
  ln_kernel<<<M_ROWS, 256, 0, stream>>>(x, ln1_s, ln1_b, h1);
  // qkv: M=4096 N=3072 K=1024, 128x128 tiles -> 32*24=768 wgs
  gemm_kernel<0, 128><<<768, 256, 0, stream>>>(h1, wqkvT, qkv, nullptr, nullptr, 4096, 3072, 1024, 24);
  rope_apply<<<dim3(TSEQ / 64, 2 * NHEAD), 256, 0, stream>>>(qkv, tab, Qb, Kb, VTb);
  attn_kernel<<<dim3(32, 32), 256, 0, stream>>>(Qb, Kb, VTb, attn);
  // wo: M=4096 N=1024 K=1024, 128x64 tiles -> 32*16=512 wgs (2 blocks/CU)
  gemm_kernel<1, 64><<<512, 256, 0, stream>>>(attn, woT, x2, nullptr, x, 4096, 1024, 1024, 16);
  ln_kernel<<<M_ROWS, 256, 0, stream>>>(x2, ln2_s, ln2_b, h2);
  // ffn1: M=4096 N=4096 K=1024, 128x128 tiles -> 32*32=1024 wgs
  gemm_kernel<2, 128><<<1024, 256, 0, stream>>>(h2, w1T, mid, b1, nullptr, 4096, 4096, 1024, 32);
  // ffn2: M=4096 N=1024 K=4096, 128x64 tiles -> 512 wgs (2 blocks/CU)
  gemm_kernel<3, 64><<<512, 256, 0, stream>>>(mid, w2T, out, b2, x2, 4096, 1024, 4096, 16);
}

// Round 7
// 231.972 us; speedup vs baseline: 2.1623x; 1.0891x over previous
//
#include <hip/hip_runtime.h>

// Decoder block: B=2 T=2048 D=1024 H=16 hd=64 HIDDEN=4096. All f32 in/out,
// bf16 MFMA internally (threshold is bf16-floor).

typedef __bf16 bf16_t;
typedef bf16_t bf16x8 __attribute__((ext_vector_type(8)));
typedef float f32x4 __attribute__((ext_vector_type(4)));

#define M_ROWS 4096   // B*T
#define DMODEL 1024
#define TSEQ   2048
#define NHEAD  16
#define HDIM   64

__device__ __forceinline__ ushort f2bf(float f) {
  union { float f; unsigned u; } v; v.f = f;
  unsigned r = (v.u + 0x7fffu + ((v.u >> 16) & 1u)) >> 16;
  return (ushort)r;
}
__device__ __forceinline__ float bf2f(ushort u) {
  union { unsigned u; float f; } v; v.u = ((unsigned)u) << 16;
  return v.f;
}
__device__ __forceinline__ unsigned cvt_pk_bf16(float a, float b) {
  unsigned r;
  asm("v_cvt_pk_bf16_f32 %0, %1, %2" : "=v"(r) : "v"(a), "v"(b));
  return r;
}
__device__ __forceinline__ void gload_lds16(const void* g, void* l) {
  __builtin_amdgcn_global_load_lds(
      (const __attribute__((address_space(1))) unsigned*)g,
      (__attribute__((address_space(3))) unsigned*)l, 16, 0, 0);
}
__device__ __forceinline__ f32x4 mfma16(bf16x8 a, bf16x8 b, f32x4 c) {
  return __builtin_amdgcn_mfma_f32_16x16x32_bf16(a, b, c, 0, 0, 0);
}
__device__ __forceinline__ float gelu_f(float x) {
  float y = 0.7978845608028654f * (x + 0.044715f * x * x * x);
  float e = __expf(2.0f * y);
  float t = 1.0f - 2.0f / (e + 1.0f);   // tanh(y), overflow-safe
  return 0.5f * x * (1.0f + t);
}

// ---------------- weight transpose + f32->bf16 -----------------------------
__global__ __launch_bounds__(256)
void transpose_bf16(const float* __restrict__ src, ushort* __restrict__ dst,
                    int K, int N) {
  __shared__ float t[32][33];
  int n0 = blockIdx.x * 32, k0 = blockIdx.y * 32;
  int tx = threadIdx.x & 31, ty = threadIdx.x >> 5;
#pragma unroll
  for (int i = 0; i < 4; i++) {
    int k = ty + i * 8;
    t[k][tx] = src[(size_t)(k0 + k) * N + n0 + tx];
  }
  __syncthreads();
#pragma unroll
  for (int i = 0; i < 4; i++) {
    int nn = ty + i * 8;
    dst[(size_t)(n0 + nn) * K + k0 + tx] = f2bf(t[tx][nn]);
  }
}

// ---------------- layernorm (f32 in, bf16 out) -----------------------------
__global__ __launch_bounds__(256)
void ln_kernel(const float* __restrict__ x, const float* __restrict__ sc,
               const float* __restrict__ bi, ushort* __restrict__ out) {
  int row = blockIdx.x;
  int tid = threadIdx.x;
  const float4 v = *(const float4*)&x[(size_t)row * DMODEL + tid * 4];
  float s = v.x + v.y + v.z + v.w;
  float s2 = v.x * v.x + v.y * v.y + v.z * v.z + v.w * v.w;
#pragma unroll
  for (int off = 32; off > 0; off >>= 1) {
    s += __shfl_down(s, off);
    s2 += __shfl_down(s2, off);
  }
  __shared__ float red[8];
  int lane = tid & 63, w = tid >> 6;
  if (lane == 0) { red[w * 2] = s; red[w * 2 + 1] = s2; }
  __syncthreads();
  float S = red[0] + red[2] + red[4] + red[6];
  float S2 = red[1] + red[3] + red[5] + red[7];
  float mu = S * (1.0f / DMODEL);
  float var = S2 * (1.0f / DMODEL) - mu * mu;
  float rs = rsqrtf(var + 1e-6f);
  float4 scv = *(const float4*)&sc[tid * 4];
  float4 biv = *(const float4*)&bi[tid * 4];
  ushort4 o;
  o.x = f2bf((v.x - mu) * rs * scv.x + biv.x);
  o.y = f2bf((v.y - mu) * rs * scv.y + biv.y);
  o.z = f2bf((v.z - mu) * rs * scv.z + biv.z);
  o.w = f2bf((v.w - mu) * rs * scv.w + biv.w);
  *(ushort4*)&out[(size_t)row * DMODEL + tid * 4] = o;
}

// ---------------- rope table -----------------------------------------------
__global__ __launch_bounds__(256)
void rope_table(const int* __restrict__ positions, float2* __restrict__ tab) {
  int i = blockIdx.x * 256 + threadIdx.x;  // T*32
  int t = i >> 5, f = i & 31;
  float inv = __expf(-(float)f * (1.0f / 32.0f) * 9.210340371976184f);
  float a = (float)positions[t] * inv;
  tab[i] = make_float2(cosf(a), sinf(a));
}

// ---------------- rope apply + QKV reshape ---------------------------------
// grid (T/64, B*H), 256 thr. Per block: 64 t-rows of one (b,h).
__global__ __launch_bounds__(256)
void rope_apply(const ushort* __restrict__ qkv, const float2* __restrict__ tab,
                ushort* __restrict__ Q, ushort* __restrict__ Kd,
                ushort* __restrict__ VT) {
  __shared__ ushort vt[64][66];
  int t0 = blockIdx.x * 64;
  int bh = blockIdx.y;
  int b = bh >> 4, h = bh & 15;
  int f = threadIdx.x & 31, tg = threadIdx.x >> 5;  // tg 0..7
#pragma unroll
  for (int i = 0; i < 8; i++) {
    int tt = tg * 8 + i;
    int t = t0 + tt;
    const ushort* qr = qkv + (size_t)(b * TSEQ + t) * 3072 + h * 64 + f;
    float2 cs = tab[t * 32 + f];
    float c = cs.x, s = cs.y;
    float q1 = bf2f(qr[0]),    q2 = bf2f(qr[32]);
    float k1 = bf2f(qr[1024]), k2 = bf2f(qr[1056]);
    ushort* Qp = Q + ((size_t)bh * TSEQ + t) * HDIM;
    ushort* Kp = Kd + ((size_t)bh * TSEQ + t) * HDIM;
    Qp[f]      = f2bf(q1 * c - q2 * s);
    Qp[f + 32] = f2bf(q1 * s + q2 * c);
    Kp[f]      = f2bf(k1 * c - k2 * s);
    Kp[f + 32] = f2bf(k1 * s + k2 * c);
    vt[f][tt]      = qr[2048];   // V needs no rope: raw bf16 copy
    vt[f + 32][tt] = qr[2080];
  }
  __syncthreads();
  int t = threadIdx.x & 63, fg = threadIdx.x >> 6;  // fg 0..3
  ushort* Vp = VT + (size_t)bh * HDIM * TSEQ + t0 + t;
#pragma unroll
  for (int j = 0; j < 16; j++) {
    int ff = fg * 16 + j;
    Vp[(size_t)ff * TSEQ] = vt[ff][t];
  }
}

// ---------------- attention (flash, causal, 4-wave LDS-staged) -------------
// (unchanged from round 6 — GEMM is the current bottleneck)
__global__ __launch_bounds__(256, 4)
void attn_kernel(const ushort* __restrict__ Q, const ushort* __restrict__ Kd,
                 const ushort* __restrict__ VT, ushort* __restrict__ O) {
  int bh = blockIdx.x;
  int qb = 31 - (int)blockIdx.y;    // longest-first
  int nt = qb + 1;                  // 64-key tiles
  int tid = threadIdx.x;
  int lane = tid & 63, w = tid >> 6;
  int qw = qb * 64 + w * 16;
  int lr = lane & 15, lg = lane >> 4;
  int q_abs = qw + lr;

  const ushort* Qb = Q + (size_t)bh * TSEQ * HDIM;
  const ushort* Kb = Kd + (size_t)bh * TSEQ * HDIM;
  const ushort* Vb = VT + (size_t)bh * HDIM * TSEQ;

  __shared__ ushort lK[2][64 * 64];
  __shared__ ushort lV[2][64 * 64];
  __shared__ ushort pt[4][16 * 64];
  ushort* myp = pt[w];

  int srow0 = tid >> 3, sch = tid & 7;

  auto stage = [&](int buf, int kt) {
#pragma unroll
    for (int c = 0; c < 2; c++) {
      int r = c * 32 + srow0;
      int gch = sch ^ (r & 7);
      gload_lds16(Kb + (size_t)(kt + r) * HDIM + gch * 8,
                  &lK[buf][c * 2048 + tid * 8]);
      gload_lds16(Vb + (size_t)r * TSEQ + kt + gch * 8,
                  &lV[buf][c * 2048 + tid * 8]);
    }
  };

  const float QS = 0.125f * 1.44269504088896340736f;
  bf16x8 aq0 = *(const bf16x8*)&Qb[(size_t)q_abs * HDIM + lg * 8];
  bf16x8 aq1 = *(const bf16x8*)&Qb[(size_t)q_abs * HDIM + 32 + lg * 8];
#pragma unroll
  for (int j = 0; j < 8; j++) {
    aq0[j] = (bf16_t)((float)aq0[j] * QS);
    aq1[j] = (bf16_t)((float)aq1[j] * QS);
  }

  float m_run = -1e30f, l_run = 0.0f;   // per-lane: stats of q-row lr
  f32x4 o[4] = {};                      // o[d][r] = O[q=lr][d*16+lg*4+r]

  stage(0, 0);
  __syncthreads();

  for (int it = 0; it < nt; ++it) {
    int kt = it * 64;
    int buf = it & 1;
    bool diag = (it == nt - 1);

    if (it + 1 < nt) stage(buf ^ 1, kt + 64);

    // QK^T (swapped): sa[cb][r] = S[k=kt+cb*16+lg*4+r][q=lr]
    f32x4 sa[4];
#pragma unroll
    for (int cb = 0; cb < 4; cb++) {
      int row = cb * 16 + lr;
      const ushort* kp = &lK[buf][row * 64];
      bf16x8 k0 = *(const bf16x8*)(kp + (((lg    ) ^ (row & 7)) << 3));
      bf16x8 k1 = *(const bf16x8*)(kp + (((lg + 4) ^ (row & 7)) << 3));
      f32x4 z = {};
      z = mfma16(k0, aq0, z);
      sa[cb] = mfma16(k1, aq1, z);
    }

    if (diag) {
#pragma unroll
      for (int cb = 0; cb < 4; cb++)
#pragma unroll
        for (int r = 0; r < 4; r++)
          if (kt + cb * 16 + lg * 4 + r > q_abs) sa[cb][r] = -1e30f;
    }

    // row max (tree + 2 shfl)
    f32x4 m4;
#pragma unroll
    for (int r = 0; r < 4; r++)
      m4[r] = fmaxf(fmaxf(sa[0][r], sa[1][r]), fmaxf(sa[2][r], sa[3][r]));
    float mx = fmaxf(fmaxf(m4[0], m4[1]), fmaxf(m4[2], m4[3]));
    mx = fmaxf(mx, __shfl_xor(mx, 16, 64));
    mx = fmaxf(mx, __shfl_xor(mx, 32, 64));
    float mn = fmaxf(m_run, mx);
    float rescale = __builtin_amdgcn_exp2f(m_run - mn);
    m_run = mn;

    // exp2 + sum + pack
    float ps = 0.0f;
    uint2 pk[4];
#pragma unroll
    for (int cb = 0; cb < 4; cb++) {
      float p0 = __builtin_amdgcn_exp2f(sa[cb][0] - mn);
      float p1 = __builtin_amdgcn_exp2f(sa[cb][1] - mn);
      float p2 = __builtin_amdgcn_exp2f(sa[cb][2] - mn);
      float p3 = __builtin_amdgcn_exp2f(sa[cb][3] - mn);
      ps += (p0 + p1) + (p2 + p3);
      pk[cb].x = cvt_pk_bf16(p0, p1);
      pk[cb].y = cvt_pk_bf16(p2, p3);
    }
    ps += __shfl_xor(ps, 16, 64);
    ps += __shfl_xor(ps, 32, 64);
    l_run = l_run * rescale + ps;

    // store P (swizzled, wave-local)
#pragma unroll
    for (int cb = 0; cb < 4; cb++)
      *(uint2*)&myp[lr * 64 + (((cb * 4 + lg) ^ lr) << 2)] = pk[cb];

    // rescale o (scalar per lane — q is lane-local)
#pragma unroll
    for (int d = 0; d < 4; d++)
#pragma unroll
      for (int r = 0; r < 4; r++) o[d][r] *= rescale;

    // read P B-fragments: lane needs P[q=lr][k = c*32 + lg*8 .. +8]
    union U8 { uint2 h[2]; bf16x8 v; };
    U8 t0, t1;
    t0.h[0] = *(const uint2*)&myp[lr * 64 + (((lg * 2    ) ^ lr) << 2)];
    t0.h[1] = *(const uint2*)&myp[lr * 64 + (((lg * 2 + 1) ^ lr) << 2)];
    t1.h[0] = *(const uint2*)&myp[lr * 64 + (((8 + lg * 2    ) ^ lr) << 2)];
    t1.h[1] = *(const uint2*)&myp[lr * 64 + (((8 + lg * 2 + 1) ^ lr) << 2)];

    // PV (swapped): o[d] += V^T_frag x P_frag  -> O^T, q = lr
#pragma unroll
    for (int d = 0; d < 4; d++) {
      int row = d * 16 + lr;
      const ushort* vp = &lV[buf][row * 64];
      bf16x8 va0 = *(const bf16x8*)(vp + (((lg    ) ^ (row & 7)) << 3));
      bf16x8 va1 = *(const bf16x8*)(vp + (((lg + 4) ^ (row & 7)) << 3));
      o[d] = mfma16(va0, t0.v, o[d]);
      o[d] = mfma16(va1, t1.v, o[d]);
    }

    __syncthreads();
  }

  int b = bh >> 4, h = bh & 15;
  float linv = 1.0f / l_run;
  size_t obase = (size_t)(b * TSEQ + qw + lr) * DMODEL + h * 64;
#pragma unroll
  for (int d = 0; d < 4; d++) {
    uint2 st;
    st.x = cvt_pk_bf16(o[d][0] * linv, o[d][1] * linv);
    st.y = cvt_pk_bf16(o[d][2] * linv, o[d][3] * linv);
    *(uint2*)&O[obase + d * 16 + lg * 4] = st;
  }
}

// ---------------- GEMM: C(M,N) = A(M,K) @ Bt(N,K)^T, bf16 in, f32 acc ------
// 2-PHASE PIPELINE (T3 minimum recipe): double-buffered LDS; per K-tile:
//   ds_read(cur) -> issue stage(next) -> MFMA(setprio) -> vmcnt(0) ->
//   raw s_barrier.  Stage latency hides under compute; NO __syncthreads()
//   full-drain before compute.  BM=128, BN template, BK=64, 4 waves 2x2.
// Chunk-XOR swizzle (chunk ^= row&7) both-sides (linear LDS dest +
// inverse-swizzled global source + swizzled read) -> conflict-free reads.
// 1-D grid, XCD swizzle (nwg % 8 == 0), bn-fastest for A-panel L2 reuse.
template <int EPI, int BN>
__global__ __launch_bounds__(256)
void gemm_kernel(const ushort* __restrict__ A, const ushort* __restrict__ Bt,
                 void* __restrict__ Cout, const float* __restrict__ bias,
                 const float* __restrict__ resid, int M, int N, int K,
                 int nbn) {
  constexpr int NF = BN / 32;           // n-frags per wave (4 or 2)
  __shared__ ushort lA[2][128 * 64];
  __shared__ ushort lB[2][BN * 64];
  int tid = threadIdx.x;
  int lane = tid & 63, w = tid >> 6;
  int wm = w >> 1, wn = w & 1;

  int nwg = gridDim.x;
  int cpx = nwg >> 3;
  int wg = ((int)blockIdx.x & 7) * cpx + ((int)blockIdx.x >> 3);
  int bm = wg / nbn, bn = wg % nbn;

  f32x4 acc[4][NF] = {};

  const ushort* Ab = A + (size_t)bm * 128 * K;
  const ushort* Bb = Bt + (size_t)bn * BN * K;
  int lrow = lane & 15, lg = lane >> 4;
  int srow = tid >> 3, sch = tid & 7;

  auto stage = [&](int buf, int k0) {
#pragma unroll
    for (int c = 0; c < 4; c++) {
      int r = c * 32 + srow;
      int gch = sch ^ (r & 7);
      gload_lds16(Ab + (size_t)r * K + k0 + gch * 8,
                  &lA[buf][c * 2048 + tid * 8]);
    }
#pragma unroll
    for (int c = 0; c < NF; c++) {
      int r = c * 32 + srow;
      int gch = sch ^ (r & 7);
      gload_lds16(Bb + (size_t)r * K + k0 + gch * 8,
                  &lB[buf][c * 2048 + tid * 8]);
    }
  };

  int nt = K >> 6;
  stage(0, 0);
  __syncthreads();   // prologue: full drain once

  for (int t = 0; t < nt; ++t) {
    int cur = t & 1;

    // ---- ds_read current tile (both k-halves) BEFORE issuing next stage ---
    bf16x8 af0[4], af1[4], bf0[NF], bf1[NF];
#pragma unroll
    for (int m = 0; m < 4; m++) {
      int row = wm * 64 + m * 16 + lrow;
      const ushort* p = &lA[cur][row * 64];
      af0[m] = *(const bf16x8*)(p + (((lg    ) ^ (row & 7)) << 3));
      af1[m] = *(const bf16x8*)(p + (((lg + 4) ^ (row & 7)) << 3));
    }
#pragma unroll
    for (int n = 0; n < NF; n++) {
      int row = wn * (BN / 2) + n * 16 + lrow;
      const ushort* p = &lB[cur][row * 64];
      bf0[n] = *(const bf16x8*)(p + (((lg    ) ^ (row & 7)) << 3));
      bf1[n] = *(const bf16x8*)(p + (((lg + 4) ^ (row & 7)) << 3));
    }

    // ---- issue next tile's async loads (fly during MFMA below) ------------
    if (t + 1 < nt) stage(cur ^ 1, (t + 1) << 6);

    // ---- MFMA cluster -----------------------------------------------------
    __builtin_amdgcn_s_setprio(1);
#pragma unroll
    for (int m = 0; m < 4; m++)
#pragma unroll
      for (int n = 0; n < NF; n++)
        acc[m][n] = mfma16(af0[m], bf0[n], acc[m][n]);
#pragma unroll
    for (int m = 0; m < 4; m++)
#pragma unroll
      for (int n = 0; n < NF; n++)
        acc[m][n] = mfma16(af1[m], bf1[n], acc[m][n]);
    __builtin_amdgcn_s_setprio(0);

    // ---- tile boundary: next tile arrived, all waves done reading cur -----
    __builtin_amdgcn_sched_barrier(0);
    asm volatile("s_waitcnt vmcnt(0)" ::: "memory");
    __builtin_amdgcn_s_barrier();
  }

#pragma unroll
  for (int m = 0; m < 4; m++) {
    int rbase = bm * 128 + wm * 64 + m * 16 + (lane >> 4) * 4;
#pragma unroll
    for (int n = 0; n < NF; n++) {
      int c = bn * BN + wn * (BN / 2) + n * 16 + (lane & 15);
#pragma unroll
      for (int r = 0; r < 4; r++) {
        float v = acc[m][n][r];
        size_t idx = (size_t)(rbase + r) * N + c;
        if constexpr (EPI == 0) {
          ((ushort*)Cout)[idx] = f2bf(v);
        } else if constexpr (EPI == 1) {
          ((float*)Cout)[idx] = v + resid[idx];
        } else if constexpr (EPI == 2) {
          ((ushort*)Cout)[idx] = f2bf(gelu_f(v + bias[c]));
        } else {
          ((float*)Cout)[idx] = v + bias[c] + resid[idx];
        }
      }
    }
  }
}

// ---------------------------------------------------------------------------
extern "C" void kernel_launch(void* const* d_in, const int* in_sizes, int n_in,
                              void* d_out, int out_size, void* d_ws,
                              size_t ws_size, hipStream_t stream) {
  const float* x      = (const float*)d_in[0];
  const int* positions = (const int*)d_in[1];
  const float* ln1_s  = (const float*)d_in[3];
  const float* ln1_b  = (const float*)d_in[4];
  const float* w_qkv  = (const float*)d_in[5];
  const float* w_o    = (const float*)d_in[6];
  const float* ln2_s  = (const float*)d_in[7];
  const float* ln2_b  = (const float*)d_in[8];
  const float* w1     = (const float*)d_in[9];
  const float* b1     = (const float*)d_in[10];
  const float* w2     = (const float*)d_in[11];
  const float* b2     = (const float*)d_in[12];
  float* out = (float*)d_out;

  char* ws = (char*)d_ws;
  size_t off = 0;
  auto nxt = [&](size_t bytes) {
    char* p = ws + off;
    off += (bytes + 255) & ~(size_t)255;
    return p;
  };
  ushort* wqkvT = (ushort*)nxt(3072ULL * 1024 * 2);
  ushort* woT   = (ushort*)nxt(1024ULL * 1024 * 2);
  ushort* w1T   = (ushort*)nxt(4096ULL * 1024 * 2);
  ushort* w2T   = (ushort*)nxt(1024ULL * 4096 * 2);
  ushort* h1    = (ushort*)nxt((size_t)M_ROWS * DMODEL * 2);
  ushort* qkv   = (ushort*)nxt((size_t)M_ROWS * 3072 * 2);
  ushort* Qb    = (ushort*)nxt(2ULL * NHEAD * TSEQ * HDIM * 2);
  ushort* Kb    = (ushort*)nxt(2ULL * NHEAD * TSEQ * HDIM * 2);
  ushort* VTb   = (ushort*)nxt(2ULL * NHEAD * TSEQ * HDIM * 2);
  ushort* attn  = (ushort*)nxt((size_t)M_ROWS * DMODEL * 2);
  float*  x2    = (float*)nxt((size_t)M_ROWS * DMODEL * 4);
  ushort* h2    = (ushort*)nxt((size_t)M_ROWS * DMODEL * 2);
  ushort* mid   = (ushort*)nxt((size_t)M_ROWS * 4096 * 2);
  float2* tab   = (float2*)nxt((size_t)TSEQ * 32 * 8);

  transpose_bf16<<<dim3(3072 / 32, 1024 / 32), 256, 0, stream>>>(w_qkv, wqkvT, 1024, 3072);
  transpose_bf16<<<dim3(1024 / 32, 1024 / 32), 256, 0, stream>>>(w_o, woT, 1024, 1024);
  transpose_bf16<<<dim3(4096 / 32, 1024 / 32), 256, 0, stream>>>(w1, w1T, 1024, 4096);
  transpose_bf16<<<dim3(1024 / 32, 4096 / 32), 256, 0, stream>>>(w2, w2T, 4096, 1024);
  rope_table<<<(TSEQ * 32) / 256, 256, 0, stream>>>(positions, tab);
  ln_kernel<<<M_ROWS, 256, 0, stream>>>(x, ln1_s, ln1_b, h1);
  // qkv: M=4096 N=3072 K=1024, 128x128 tiles -> 768 wgs
  gemm_kernel<0, 128><<<768, 256, 0, stream>>>(h1, wqkvT, qkv, nullptr, nullptr, 4096, 3072, 1024, 24);
  rope_apply<<<dim3(TSEQ / 64, 2 * NHEAD), 256, 0, stream>>>(qkv, tab, Qb, Kb, VTb);
  attn_kernel<<<dim3(32, 32), 256, 0, stream>>>(Qb, Kb, VTb, attn);
  // wo: M=4096 N=1024 K=1024, 128x64 tiles -> 512 wgs
  gemm_kernel<1, 64><<<512, 256, 0, stream>>>(attn, woT, x2, nullptr, x, 4096, 1024, 1024, 16);
  ln_kernel<<<M_ROWS, 256, 0, stream>>>(x2, ln2_s, ln2_b, h2);
  // ffn1: M=4096 N=4096 K=1024, 128x128 tiles -> 1024 wgs
  gemm_kernel<2, 128><<<1024, 256, 0, stream>>>(h2, w1T, mid, b1, nullptr, 4096, 4096, 1024, 32);
  // ffn2: M=4096 N=1024 K=4096, 128x64 tiles -> 512 wgs
  gemm_kernel<3, 64><<<512, 256, 0, stream>>>(mid, w2T, out, b2, x2, 4096, 1024, 4096, 16);
}

// Round 8
// 224.224 us; speedup vs baseline: 2.2371x; 1.0346x over previous
//
#include <hip/hip_runtime.h>

// Decoder block: B=2 T=2048 D=1024 H=16 hd=64 HIDDEN=4096. All f32 in/out,
// bf16 MFMA internally (threshold is bf16-floor).

typedef __bf16 bf16_t;
typedef bf16_t bf16x8 __attribute__((ext_vector_type(8)));
typedef float f32x4 __attribute__((ext_vector_type(4)));

#define M_ROWS 4096   // B*T
#define DMODEL 1024
#define TSEQ   2048
#define NHEAD  16
#define HDIM   64

__device__ __forceinline__ ushort f2bf(float f) {
  union { float f; unsigned u; } v; v.f = f;
  unsigned r = (v.u + 0x7fffu + ((v.u >> 16) & 1u)) >> 16;
  return (ushort)r;
}
__device__ __forceinline__ float bf2f(ushort u) {
  union { unsigned u; float f; } v; v.u = ((unsigned)u) << 16;
  return v.f;
}
__device__ __forceinline__ unsigned cvt_pk_bf16(float a, float b) {
  unsigned r;
  asm("v_cvt_pk_bf16_f32 %0, %1, %2" : "=v"(r) : "v"(a), "v"(b));
  return r;
}
__device__ __forceinline__ void gload_lds16(const void* g, void* l) {
  __builtin_amdgcn_global_load_lds(
      (const __attribute__((address_space(1))) unsigned*)g,
      (__attribute__((address_space(3))) unsigned*)l, 16, 0, 0);
}
__device__ __forceinline__ f32x4 mfma16(bf16x8 a, bf16x8 b, f32x4 c) {
  return __builtin_amdgcn_mfma_f32_16x16x32_bf16(a, b, c, 0, 0, 0);
}
__device__ __forceinline__ float gelu_f(float x) {
  float y = 0.7978845608028654f * (x + 0.044715f * x * x * x);
  float e = __expf(2.0f * y);
  float t = 1.0f - 2.0f / (e + 1.0f);   // tanh(y), overflow-safe
  return 0.5f * x * (1.0f + t);
}

// ---------------- weight transpose + f32->bf16 -----------------------------
__global__ __launch_bounds__(256)
void transpose_bf16(const float* __restrict__ src, ushort* __restrict__ dst,
                    int K, int N) {
  __shared__ float t[32][33];
  int n0 = blockIdx.x * 32, k0 = blockIdx.y * 32;
  int tx = threadIdx.x & 31, ty = threadIdx.x >> 5;
#pragma unroll
  for (int i = 0; i < 4; i++) {
    int k = ty + i * 8;
    t[k][tx] = src[(size_t)(k0 + k) * N + n0 + tx];
  }
  __syncthreads();
#pragma unroll
  for (int i = 0; i < 4; i++) {
    int nn = ty + i * 8;
    dst[(size_t)(n0 + nn) * K + k0 + tx] = f2bf(t[tx][nn]);
  }
}

// ---------------- layernorm (f32 in, bf16 out) -----------------------------
__global__ __launch_bounds__(256)
void ln_kernel(const float* __restrict__ x, const float* __restrict__ sc,
               const float* __restrict__ bi, ushort* __restrict__ out) {
  int row = blockIdx.x;
  int tid = threadIdx.x;
  const float4 v = *(const float4*)&x[(size_t)row * DMODEL + tid * 4];
  float s = v.x + v.y + v.z + v.w;
  float s2 = v.x * v.x + v.y * v.y + v.z * v.z + v.w * v.w;
#pragma unroll
  for (int off = 32; off > 0; off >>= 1) {
    s += __shfl_down(s, off);
    s2 += __shfl_down(s2, off);
  }
  __shared__ float red[8];
  int lane = tid & 63, w = tid >> 6;
  if (lane == 0) { red[w * 2] = s; red[w * 2 + 1] = s2; }
  __syncthreads();
  float S = red[0] + red[2] + red[4] + red[6];
  float S2 = red[1] + red[3] + red[5] + red[7];
  float mu = S * (1.0f / DMODEL);
  float var = S2 * (1.0f / DMODEL) - mu * mu;
  float rs = rsqrtf(var + 1e-6f);
  float4 scv = *(const float4*)&sc[tid * 4];
  float4 biv = *(const float4*)&bi[tid * 4];
  ushort4 o;
  o.x = f2bf((v.x - mu) * rs * scv.x + biv.x);
  o.y = f2bf((v.y - mu) * rs * scv.y + biv.y);
  o.z = f2bf((v.z - mu) * rs * scv.z + biv.z);
  o.w = f2bf((v.w - mu) * rs * scv.w + biv.w);
  *(ushort4*)&out[(size_t)row * DMODEL + tid * 4] = o;
}

// ---------------- rope table -----------------------------------------------
__global__ __launch_bounds__(256)
void rope_table(const int* __restrict__ positions, float2* __restrict__ tab) {
  int i = blockIdx.x * 256 + threadIdx.x;  // T*32
  int t = i >> 5, f = i & 31;
  float inv = __expf(-(float)f * (1.0f / 32.0f) * 9.210340371976184f);
  float a = (float)positions[t] * inv;
  tab[i] = make_float2(cosf(a), sinf(a));
}

// ---------------- rope apply + QKV reshape ---------------------------------
__global__ __launch_bounds__(256)
void rope_apply(const ushort* __restrict__ qkv, const float2* __restrict__ tab,
                ushort* __restrict__ Q, ushort* __restrict__ Kd,
                ushort* __restrict__ VT) {
  __shared__ ushort vt[64][66];
  int t0 = blockIdx.x * 64;
  int bh = blockIdx.y;
  int b = bh >> 4, h = bh & 15;
  int f = threadIdx.x & 31, tg = threadIdx.x >> 5;  // tg 0..7
#pragma unroll
  for (int i = 0; i < 8; i++) {
    int tt = tg * 8 + i;
    int t = t0 + tt;
    const ushort* qr = qkv + (size_t)(b * TSEQ + t) * 3072 + h * 64 + f;
    float2 cs = tab[t * 32 + f];
    float c = cs.x, s = cs.y;
    float q1 = bf2f(qr[0]),    q2 = bf2f(qr[32]);
    float k1 = bf2f(qr[1024]), k2 = bf2f(qr[1056]);
    ushort* Qp = Q + ((size_t)bh * TSEQ + t) * HDIM;
    ushort* Kp = Kd + ((size_t)bh * TSEQ + t) * HDIM;
    Qp[f]      = f2bf(q1 * c - q2 * s);
    Qp[f + 32] = f2bf(q1 * s + q2 * c);
    Kp[f]      = f2bf(k1 * c - k2 * s);
    Kp[f + 32] = f2bf(k1 * s + k2 * c);
    vt[f][tt]      = qr[2048];   // V needs no rope: raw bf16 copy
    vt[f + 32][tt] = qr[2080];
  }
  __syncthreads();
  int t = threadIdx.x & 63, fg = threadIdx.x >> 6;  // fg 0..3
  ushort* Vp = VT + (size_t)bh * HDIM * TSEQ + t0 + t;
#pragma unroll
  for (int j = 0; j < 16; j++) {
    int ff = fg * 16 + j;
    Vp[(size_t)ff * TSEQ] = vt[ff][t];
  }
}

// ---------------- attention (flash, causal, 4-wave LDS-staged) -------------
// (unchanged — GEMM is the current bottleneck)
__global__ __launch_bounds__(256, 4)
void attn_kernel(const ushort* __restrict__ Q, const ushort* __restrict__ Kd,
                 const ushort* __restrict__ VT, ushort* __restrict__ O) {
  int bh = blockIdx.x;
  int qb = 31 - (int)blockIdx.y;    // longest-first
  int nt = qb + 1;                  // 64-key tiles
  int tid = threadIdx.x;
  int lane = tid & 63, w = tid >> 6;
  int qw = qb * 64 + w * 16;
  int lr = lane & 15, lg = lane >> 4;
  int q_abs = qw + lr;

  const ushort* Qb = Q + (size_t)bh * TSEQ * HDIM;
  const ushort* Kb = Kd + (size_t)bh * TSEQ * HDIM;
  const ushort* Vb = VT + (size_t)bh * HDIM * TSEQ;

  __shared__ ushort lK[2][64 * 64];
  __shared__ ushort lV[2][64 * 64];
  __shared__ ushort pt[4][16 * 64];
  ushort* myp = pt[w];

  int srow0 = tid >> 3, sch = tid & 7;

  auto stage = [&](int buf, int kt) {
#pragma unroll
    for (int c = 0; c < 2; c++) {
      int r = c * 32 + srow0;
      int gch = sch ^ (r & 7);
      gload_lds16(Kb + (size_t)(kt + r) * HDIM + gch * 8,
                  &lK[buf][c * 2048 + tid * 8]);
      gload_lds16(Vb + (size_t)r * TSEQ + kt + gch * 8,
                  &lV[buf][c * 2048 + tid * 8]);
    }
  };

  const float QS = 0.125f * 1.44269504088896340736f;
  bf16x8 aq0 = *(const bf16x8*)&Qb[(size_t)q_abs * HDIM + lg * 8];
  bf16x8 aq1 = *(const bf16x8*)&Qb[(size_t)q_abs * HDIM + 32 + lg * 8];
#pragma unroll
  for (int j = 0; j < 8; j++) {
    aq0[j] = (bf16_t)((float)aq0[j] * QS);
    aq1[j] = (bf16_t)((float)aq1[j] * QS);
  }

  float m_run = -1e30f, l_run = 0.0f;   // per-lane: stats of q-row lr
  f32x4 o[4] = {};                      // o[d][r] = O[q=lr][d*16+lg*4+r]

  stage(0, 0);
  __syncthreads();

  for (int it = 0; it < nt; ++it) {
    int kt = it * 64;
    int buf = it & 1;
    bool diag = (it == nt - 1);

    if (it + 1 < nt) stage(buf ^ 1, kt + 64);

    // QK^T (swapped): sa[cb][r] = S[k=kt+cb*16+lg*4+r][q=lr]
    f32x4 sa[4];
#pragma unroll
    for (int cb = 0; cb < 4; cb++) {
      int row = cb * 16 + lr;
      const ushort* kp = &lK[buf][row * 64];
      bf16x8 k0 = *(const bf16x8*)(kp + (((lg    ) ^ (row & 7)) << 3));
      bf16x8 k1 = *(const bf16x8*)(kp + (((lg + 4) ^ (row & 7)) << 3));
      f32x4 z = {};
      z = mfma16(k0, aq0, z);
      sa[cb] = mfma16(k1, aq1, z);
    }

    if (diag) {
#pragma unroll
      for (int cb = 0; cb < 4; cb++)
#pragma unroll
        for (int r = 0; r < 4; r++)
          if (kt + cb * 16 + lg * 4 + r > q_abs) sa[cb][r] = -1e30f;
    }

    // row max (tree + 2 shfl)
    f32x4 m4;
#pragma unroll
    for (int r = 0; r < 4; r++)
      m4[r] = fmaxf(fmaxf(sa[0][r], sa[1][r]), fmaxf(sa[2][r], sa[3][r]));
    float mx = fmaxf(fmaxf(m4[0], m4[1]), fmaxf(m4[2], m4[3]));
    mx = fmaxf(mx, __shfl_xor(mx, 16, 64));
    mx = fmaxf(mx, __shfl_xor(mx, 32, 64));
    float mn = fmaxf(m_run, mx);
    float rescale = __builtin_amdgcn_exp2f(m_run - mn);
    m_run = mn;

    // exp2 + sum + pack
    float ps = 0.0f;
    uint2 pk[4];
#pragma unroll
    for (int cb = 0; cb < 4; cb++) {
      float p0 = __builtin_amdgcn_exp2f(sa[cb][0] - mn);
      float p1 = __builtin_amdgcn_exp2f(sa[cb][1] - mn);
      float p2 = __builtin_amdgcn_exp2f(sa[cb][2] - mn);
      float p3 = __builtin_amdgcn_exp2f(sa[cb][3] - mn);
      ps += (p0 + p1) + (p2 + p3);
      pk[cb].x = cvt_pk_bf16(p0, p1);
      pk[cb].y = cvt_pk_bf16(p2, p3);
    }
    ps += __shfl_xor(ps, 16, 64);
    ps += __shfl_xor(ps, 32, 64);
    l_run = l_run * rescale + ps;

    // store P (swizzled, wave-local)
#pragma unroll
    for (int cb = 0; cb < 4; cb++)
      *(uint2*)&myp[lr * 64 + (((cb * 4 + lg) ^ lr) << 2)] = pk[cb];

    // rescale o (scalar per lane — q is lane-local)
#pragma unroll
    for (int d = 0; d < 4; d++)
#pragma unroll
      for (int r = 0; r < 4; r++) o[d][r] *= rescale;

    // read P B-fragments: lane needs P[q=lr][k = c*32 + lg*8 .. +8]
    union U8 { uint2 h[2]; bf16x8 v; };
    U8 t0, t1;
    t0.h[0] = *(const uint2*)&myp[lr * 64 + (((lg * 2    ) ^ lr) << 2)];
    t0.h[1] = *(const uint2*)&myp[lr * 64 + (((lg * 2 + 1) ^ lr) << 2)];
    t1.h[0] = *(const uint2*)&myp[lr * 64 + (((8 + lg * 2    ) ^ lr) << 2)];
    t1.h[1] = *(const uint2*)&myp[lr * 64 + (((8 + lg * 2 + 1) ^ lr) << 2)];

    // PV (swapped): o[d] += V^T_frag x P_frag  -> O^T, q = lr
#pragma unroll
    for (int d = 0; d < 4; d++) {
      int row = d * 16 + lr;
      const ushort* vp = &lV[buf][row * 64];
      bf16x8 va0 = *(const bf16x8*)(vp + (((lg    ) ^ (row & 7)) << 3));
      bf16x8 va1 = *(const bf16x8*)(vp + (((lg + 4) ^ (row & 7)) << 3));
      o[d] = mfma16(va0, t0.v, o[d]);
      o[d] = mfma16(va1, t1.v, o[d]);
    }

    __syncthreads();
  }

  int b = bh >> 4, h = bh & 15;
  float linv = 1.0f / l_run;
  size_t obase = (size_t)(b * TSEQ + qw + lr) * DMODEL + h * 64;
#pragma unroll
  for (int d = 0; d < 4; d++) {
    uint2 st;
    st.x = cvt_pk_bf16(o[d][0] * linv, o[d][1] * linv);
    st.y = cvt_pk_bf16(o[d][2] * linv, o[d][3] * linv);
    *(uint2*)&O[obase + d * 16 + lg * 4] = st;
  }
}

// ---------------- GEMM 256x256: 8 waves, BK=64, 2-phase pipeline -----------
// 512 thr = 8 waves (2M x 4N); per-wave output 128x64 (acc[8][4]).
// Dynamic LDS 128 KiB: lA[2][256*64] + lB[2][256*64].
// Per K-tile: ds_read(ks0) -> issue 8 async stages(next) -> 32 MFMA ->
//   ds_read(ks1) -> 32 MFMA -> sched_barrier -> vmcnt(0) -> s_barrier.
// Chunk-XOR swizzle (chunk ^= row&7) both-sides; XCD-swizzled 1-D grid.
template <int EPI>
__global__ __launch_bounds__(512)
void gemm256(const ushort* __restrict__ A, const ushort* __restrict__ Bt,
             void* __restrict__ Cout, const float* __restrict__ bias,
             const float* __restrict__ resid, int M, int N, int K, int nbn) {
  extern __shared__ ushort smem[];
  ushort* lA = smem;            // [2][256*64]
  ushort* lB = smem + 32768;    // [2][256*64]

  int tid = threadIdx.x;
  int lane = tid & 63, w = tid >> 6;
  int wm = w >> 2, wn = w & 3;          // 2 x 4 wave grid
  int lrow = lane & 15, lg = lane >> 4;

  int nwg = gridDim.x;
  int cpx = nwg >> 3;
  int wg = ((int)blockIdx.x & 7) * cpx + ((int)blockIdx.x >> 3);
  int bm = wg / nbn, bn = wg % nbn;

  const ushort* Ab = A + (size_t)bm * 256 * K;
  const ushort* Bb = Bt + (size_t)bn * 256 * K;
  int srow = tid >> 3, sch = tid & 7;   // staging: 64 rows / call

  auto stage = [&](int buf, int k0) {
#pragma unroll
    for (int c = 0; c < 4; c++) {
      int r = c * 64 + srow;
      int gch = sch ^ (r & 7);
      gload_lds16(Ab + (size_t)r * K + k0 + gch * 8,
                  &lA[buf * 16384 + c * 4096 + tid * 8]);
    }
#pragma unroll
    for (int c = 0; c < 4; c++) {
      int r = c * 64 + srow;
      int gch = sch ^ (r & 7);
      gload_lds16(Bb + (size_t)r * K + k0 + gch * 8,
                  &lB[buf * 16384 + c * 4096 + tid * 8]);
    }
  };

  f32x4 acc[8][4] = {};

  int nt = K >> 6;
  stage(0, 0);
  __syncthreads();   // prologue: full drain once

  for (int t = 0; t < nt; ++t) {
    int cur = t & 1;
    const ushort* la = &lA[cur * 16384];
    const ushort* lb = &lB[cur * 16384];

    bf16x8 af[8], bf[4];
    // ---- k-substep 0: reads (chunk base lg) ----
#pragma unroll
    for (int m = 0; m < 8; m++) {
      int row = wm * 128 + m * 16 + lrow;
      af[m] = *(const bf16x8*)&la[row * 64 + ((lg ^ (row & 7)) << 3)];
    }
#pragma unroll
    for (int n = 0; n < 4; n++) {
      int row = wn * 64 + n * 16 + lrow;
      bf[n] = *(const bf16x8*)&lb[row * 64 + ((lg ^ (row & 7)) << 3)];
    }

    // ---- issue next tile's async loads (fly during MFMAs below) ----
    if (t + 1 < nt) stage(cur ^ 1, (t + 1) << 6);

    __builtin_amdgcn_s_setprio(1);
#pragma unroll
    for (int m = 0; m < 8; m++)
#pragma unroll
      for (int n = 0; n < 4; n++)
        acc[m][n] = mfma16(af[m], bf[n], acc[m][n]);
    __builtin_amdgcn_s_setprio(0);

    // ---- k-substep 1: reads (chunk base 4+lg) ----
#pragma unroll
    for (int m = 0; m < 8; m++) {
      int row = wm * 128 + m * 16 + lrow;
      af[m] = *(const bf16x8*)&la[row * 64 + (((4 + lg) ^ (row & 7)) << 3)];
    }
#pragma unroll
    for (int n = 0; n < 4; n++) {
      int row = wn * 64 + n * 16 + lrow;
      bf[n] = *(const bf16x8*)&lb[row * 64 + (((4 + lg) ^ (row & 7)) << 3)];
    }
    __builtin_amdgcn_s_setprio(1);
#pragma unroll
    for (int m = 0; m < 8; m++)
#pragma unroll
      for (int n = 0; n < 4; n++)
        acc[m][n] = mfma16(af[m], bf[n], acc[m][n]);
    __builtin_amdgcn_s_setprio(0);

    // ---- tile boundary ----
    __builtin_amdgcn_sched_barrier(0);
    asm volatile("s_waitcnt vmcnt(0)" ::: "memory");
    __builtin_amdgcn_s_barrier();
  }

#pragma unroll
  for (int m = 0; m < 8; m++) {
    int rbase = bm * 256 + wm * 128 + m * 16 + lg * 4;
#pragma unroll
    for (int n = 0; n < 4; n++) {
      int c = bn * 256 + wn * 64 + n * 16 + lrow;
#pragma unroll
      for (int r = 0; r < 4; r++) {
        float v = acc[m][n][r];
        size_t idx = (size_t)(rbase + r) * N + c;
        if constexpr (EPI == 0) {
          ((ushort*)Cout)[idx] = f2bf(v);
        } else if constexpr (EPI == 1) {
          ((float*)Cout)[idx] = v + resid[idx];
        } else if constexpr (EPI == 2) {
          ((ushort*)Cout)[idx] = f2bf(gelu_f(v + bias[c]));
        } else {
          ((float*)Cout)[idx] = v + bias[c] + resid[idx];
        }
      }
    }
  }
}

// ---------------- GEMM 128xBN (kept for wo / ffn2, N=1024) -----------------
template <int EPI, int BN>
__global__ __launch_bounds__(256)
void gemm_kernel(const ushort* __restrict__ A, const ushort* __restrict__ Bt,
                 void* __restrict__ Cout, const float* __restrict__ bias,
                 const float* __restrict__ resid, int M, int N, int K,
                 int nbn) {
  constexpr int NF = BN / 32;           // n-frags per wave (4 or 2)
  __shared__ ushort lA[2][128 * 64];
  __shared__ ushort lB[2][BN * 64];
  int tid = threadIdx.x;
  int lane = tid & 63, w = tid >> 6;
  int wm = w >> 1, wn = w & 1;

  int nwg = gridDim.x;
  int cpx = nwg >> 3;
  int wg = ((int)blockIdx.x & 7) * cpx + ((int)blockIdx.x >> 3);
  int bm = wg / nbn, bn = wg % nbn;

  f32x4 acc[4][NF] = {};

  const ushort* Ab = A + (size_t)bm * 128 * K;
  const ushort* Bb = Bt + (size_t)bn * BN * K;
  int lrow = lane & 15, lg = lane >> 4;
  int srow = tid >> 3, sch = tid & 7;

  auto stage = [&](int buf, int k0) {
#pragma unroll
    for (int c = 0; c < 4; c++) {
      int r = c * 32 + srow;
      int gch = sch ^ (r & 7);
      gload_lds16(Ab + (size_t)r * K + k0 + gch * 8,
                  &lA[buf][c * 2048 + tid * 8]);
    }
#pragma unroll
    for (int c = 0; c < NF; c++) {
      int r = c * 32 + srow;
      int gch = sch ^ (r & 7);
      gload_lds16(Bb + (size_t)r * K + k0 + gch * 8,
                  &lB[buf][c * 2048 + tid * 8]);
    }
  };

  int nt = K >> 6;
  stage(0, 0);
  __syncthreads();   // prologue: full drain once

  for (int t = 0; t < nt; ++t) {
    int cur = t & 1;

    bf16x8 af0[4], af1[4], bf0[NF], bf1[NF];
#pragma unroll
    for (int m = 0; m < 4; m++) {
      int row = wm * 64 + m * 16 + lrow;
      const ushort* p = &lA[cur][row * 64];
      af0[m] = *(const bf16x8*)(p + (((lg    ) ^ (row & 7)) << 3));
      af1[m] = *(const bf16x8*)(p + (((lg + 4) ^ (row & 7)) << 3));
    }
#pragma unroll
    for (int n = 0; n < NF; n++) {
      int row = wn * (BN / 2) + n * 16 + lrow;
      const ushort* p = &lB[cur][row * 64];
      bf0[n] = *(const bf16x8*)(p + (((lg    ) ^ (row & 7)) << 3));
      bf1[n] = *(const bf16x8*)(p + (((lg + 4) ^ (row & 7)) << 3));
    }

    if (t + 1 < nt) stage(cur ^ 1, (t + 1) << 6);

    __builtin_amdgcn_s_setprio(1);
#pragma unroll
    for (int m = 0; m < 4; m++)
#pragma unroll
      for (int n = 0; n < NF; n++)
        acc[m][n] = mfma16(af0[m], bf0[n], acc[m][n]);
#pragma unroll
    for (int m = 0; m < 4; m++)
#pragma unroll
      for (int n = 0; n < NF; n++)
        acc[m][n] = mfma16(af1[m], bf1[n], acc[m][n]);
    __builtin_amdgcn_s_setprio(0);

    __builtin_amdgcn_sched_barrier(0);
    asm volatile("s_waitcnt vmcnt(0)" ::: "memory");
    __builtin_amdgcn_s_barrier();
  }

#pragma unroll
  for (int m = 0; m < 4; m++) {
    int rbase = bm * 128 + wm * 64 + m * 16 + (lane >> 4) * 4;
#pragma unroll
    for (int n = 0; n < NF; n++) {
      int c = bn * BN + wn * (BN / 2) + n * 16 + (lane & 15);
#pragma unroll
      for (int r = 0; r < 4; r++) {
        float v = acc[m][n][r];
        size_t idx = (size_t)(rbase + r) * N + c;
        if constexpr (EPI == 0) {
          ((ushort*)Cout)[idx] = f2bf(v);
        } else if constexpr (EPI == 1) {
          ((float*)Cout)[idx] = v + resid[idx];
        } else if constexpr (EPI == 2) {
          ((ushort*)Cout)[idx] = f2bf(gelu_f(v + bias[c]));
        } else {
          ((float*)Cout)[idx] = v + bias[c] + resid[idx];
        }
      }
    }
  }
}

// ---------------------------------------------------------------------------
extern "C" void kernel_launch(void* const* d_in, const int* in_sizes, int n_in,
                              void* d_out, int out_size, void* d_ws,
                              size_t ws_size, hipStream_t stream) {
  const float* x      = (const float*)d_in[0];
  const int* positions = (const int*)d_in[1];
  const float* ln1_s  = (const float*)d_in[3];
  const float* ln1_b  = (const float*)d_in[4];
  const float* w_qkv  = (const float*)d_in[5];
  const float* w_o    = (const float*)d_in[6];
  const float* ln2_s  = (const float*)d_in[7];
  const float* ln2_b  = (const float*)d_in[8];
  const float* w1     = (const float*)d_in[9];
  const float* b1     = (const float*)d_in[10];
  const float* w2     = (const float*)d_in[11];
  const float* b2     = (const float*)d_in[12];
  float* out = (float*)d_out;

  char* ws = (char*)d_ws;
  size_t off = 0;
  auto nxt = [&](size_t bytes) {
    char* p = ws + off;
    off += (bytes + 255) & ~(size_t)255;
    return p;
  };
  ushort* wqkvT = (ushort*)nxt(3072ULL * 1024 * 2);
  ushort* woT   = (ushort*)nxt(1024ULL * 1024 * 2);
  ushort* w1T   = (ushort*)nxt(4096ULL * 1024 * 2);
  ushort* w2T   = (ushort*)nxt(1024ULL * 4096 * 2);
  ushort* h1    = (ushort*)nxt((size_t)M_ROWS * DMODEL * 2);
  ushort* qkv   = (ushort*)nxt((size_t)M_ROWS * 3072 * 2);
  ushort* Qb    = (ushort*)nxt(2ULL * NHEAD * TSEQ * HDIM * 2);
  ushort* Kb    = (ushort*)nxt(2ULL * NHEAD * TSEQ * HDIM * 2);
  ushort* VTb   = (ushort*)nxt(2ULL * NHEAD * TSEQ * HDIM * 2);
  ushort* attn  = (ushort*)nxt((size_t)M_ROWS * DMODEL * 2);
  float*  x2    = (float*)nxt((size_t)M_ROWS * DMODEL * 4);
  ushort* h2    = (ushort*)nxt((size_t)M_ROWS * DMODEL * 2);
  ushort* mid   = (ushort*)nxt((size_t)M_ROWS * 4096 * 2);
  float2* tab   = (float2*)nxt((size_t)TSEQ * 32 * 8);

  // allow 128 KiB dynamic LDS for the 256x256 GEMMs (capture-safe host call)
  (void)hipFuncSetAttribute((const void*)gemm256<0>,
                            hipFuncAttributeMaxDynamicSharedMemorySize, 131072);
  (void)hipFuncSetAttribute((const void*)gemm256<2>,
                            hipFuncAttributeMaxDynamicSharedMemorySize, 131072);

  transpose_bf16<<<dim3(3072 / 32, 1024 / 32), 256, 0, stream>>>(w_qkv, wqkvT, 1024, 3072);
  transpose_bf16<<<dim3(1024 / 32, 1024 / 32), 256, 0, stream>>>(w_o, woT, 1024, 1024);
  transpose_bf16<<<dim3(4096 / 32, 1024 / 32), 256, 0, stream>>>(w1, w1T, 1024, 4096);
  transpose_bf16<<<dim3(1024 / 32, 4096 / 32), 256, 0, stream>>>(w2, w2T, 4096, 1024);
  rope_table<<<(TSEQ * 32) / 256, 256, 0, stream>>>(positions, tab);
  ln_kernel<<<M_ROWS, 256, 0, stream>>>(x, ln1_s, ln1_b, h1);
  // qkv: M=4096 N=3072 K=1024, 256x256 tiles -> 16*12=192 wgs
  gemm256<0><<<192, 512, 131072, stream>>>(h1, wqkvT, qkv, nullptr, nullptr, 4096, 3072, 1024, 12);
  rope_apply<<<dim3(TSEQ / 64, 2 * NHEAD), 256, 0, stream>>>(qkv, tab, Qb, Kb, VTb);
  attn_kernel<<<dim3(32, 32), 256, 0, stream>>>(Qb, Kb, VTb, attn);
  // wo: M=4096 N=1024 K=1024, 128x64 tiles -> 512 wgs
  gemm_kernel<1, 64><<<512, 256, 0, stream>>>(attn, woT, x2, nullptr, x, 4096, 1024, 1024, 16);
  ln_kernel<<<M_ROWS, 256, 0, stream>>>(x2, ln2_s, ln2_b, h2);
  // ffn1: M=4096 N=4096 K=1024, 256x256 tiles -> 16*16=256 wgs (1/CU)
  gemm256<2><<<256, 512, 131072, stream>>>(h2, w1T, mid, b1, nullptr, 4096, 4096, 1024, 16);
  // ffn2: M=4096 N=1024 K=4096, 128x64 tiles -> 512 wgs
  gemm_kernel<3, 64><<<512, 256, 0, stream>>>(mid, w2T, out, b2, x2, 4096, 1024, 4096, 16);
}